// Round 18
// baseline (776.485 us; speedup 1.0000x reference)
//
#include <hip/hip_runtime.h>
#include <math.h>

typedef unsigned short u16;
typedef unsigned int u32;
typedef __bf16 bfx8 __attribute__((ext_vector_type(8)));
typedef float f32x4 __attribute__((ext_vector_type(4)));

#define NB 16
#define SS 512
#define NHD 16
#define DD 64
#define HD 1024
#define NROWS 8192
#define NEL 8388608  // 8192*1024

// scalar slots in ws (floats)
#define SL_AX_X 0
#define SL_AX_V 1
#define SL_MINSUM 2
#define SL_AX_CTX 3
#define SL_AX_QT 4   // 16 slots
#define SL_AX_KT 20  // 16 slots

struct PLA { float m[12]; float c[12]; float a[12]; };
struct WP { const float* W[4]; };
struct GP { const float* bias[3]; float* ax[3]; };

__device__ __forceinline__ u16 f2b_exact(float f) { return (u16)(__float_as_uint(f) >> 16); }
__device__ __forceinline__ float mk_scale(float mx) { float s = mx / 127.0f; return (s == 0.0f) ? 1.0f : s; }
__device__ __forceinline__ float quant_val(float x, float s) {
  return fminf(fmaxf(rintf(x / s), -127.0f), 127.0f);
}
// pla3: single-load PLA (guess by fma+trunc, no correction load) — accepted ~1e-4 ctx noise.
__device__ __forceinline__ float pla3(float xc, const float2* tbl2) {
  int idx = (int)__fmaf_rn(xc, 1.2f, 12.0f);
  idx = idx < 0 ? 0 : (idx > 11 ? 11 : idx);
  float2 mc = tbl2[idx];
  return __fmaf_rn(mc.x, xc, mc.y);
}

// async global->LDS, 16B per lane (m97 staging primitive)
__device__ __forceinline__ void gload16(const u16* g, u16* l) {
  __builtin_amdgcn_global_load_lds(
      (const __attribute__((address_space(1))) unsigned int*)g,
      (__attribute__((address_space(3))) unsigned int*)l, 16, 0, 0);
}

// fused: blocks [0,4096) = per-row weight quant (4 matrices); 4096 = scal init;
// (4096,4608] = hs absmax partials (plain stores).
__global__ void k_prep(WP wp, float* __restrict__ sw, u16* __restrict__ wout,
                       float* __restrict__ scal, const float* __restrict__ hs,
                       float* __restrict__ hsax) {
  __shared__ float red[4];
  __shared__ float sbc;
  int tid = threadIdx.x;
  if (blockIdx.x == 4096) {
    if (tid < 64) scal[tid] = (tid == SL_MINSUM) ? __uint_as_float(0x7f800000u) : 0.0f;
    return;
  }
  if (blockIdx.x > 4096) {
    int pb = blockIdx.x - 4097;
    int t = pb * 256 + tid;
    const float4* x4 = (const float4*)hs;
    float m = 0.f;
    for (int j = t; j < (NEL >> 2); j += 512 * 256) {
      float4 v = x4[j];
      m = fmaxf(m, fmaxf(fmaxf(fabsf(v.x), fabsf(v.y)), fmaxf(fabsf(v.z), fabsf(v.w))));
    }
#pragma unroll
    for (int off = 32; off > 0; off >>= 1) m = fmaxf(m, __shfl_down(m, off));
    if ((tid & 63) == 0) red[tid >> 6] = m;
    __syncthreads();
    if (tid == 0) hsax[pb] = fmaxf(fmaxf(red[0], red[1]), fmaxf(red[2], red[3]));
    return;
  }
  int mat = blockIdx.x >> 10, r = blockIdx.x & 1023;
  const float* W = wp.W[mat];
  float4 v = ((const float4*)(W + (size_t)r * 1024))[tid];
  float m = fmaxf(fmaxf(fabsf(v.x), fabsf(v.y)), fmaxf(fabsf(v.z), fabsf(v.w)));
#pragma unroll
  for (int off = 32; off > 0; off >>= 1) m = fmaxf(m, __shfl_down(m, off));
  int lane = tid & 63, wv = tid >> 6;
  if (lane == 0) red[wv] = m;
  __syncthreads();
  if (tid == 0) sbc = mk_scale(fmaxf(fmaxf(red[0], red[1]), fmaxf(red[2], red[3])));
  __syncthreads();
  float s = sbc;
  if (tid == 0) sw[mat * 1024 + r] = s;
  u16 o0 = f2b_exact(quant_val(v.x, s));
  u16 o1 = f2b_exact(quant_val(v.y, s));
  u16 o2 = f2b_exact(quant_val(v.z, s));
  u16 o3 = f2b_exact(quant_val(v.w, s));
  u32* orow = (u32*)(wout + (size_t)mat * 1048576 + (size_t)r * 1024);
  orow[tid * 2] = (u32)o0 | ((u32)o1 << 16);
  orow[tid * 2 + 1] = (u32)o2 | ((u32)o3 << 16);
}

// quantize hs with scale from 512 partials; block 0 publishes scal[SL_AX_X]
__global__ void k_quant_hs(const float* __restrict__ x, u16* __restrict__ o,
                           const float* __restrict__ hsax, float* __restrict__ scal) {
  float m = 0.f;
  for (int i = threadIdx.x; i < 512; i += 256) m = fmaxf(m, hsax[i]);
#pragma unroll
  for (int off = 32; off > 0; off >>= 1) m = fmaxf(m, __shfl_down(m, off));
  __shared__ float red[4];
  if ((threadIdx.x & 63) == 0) red[threadIdx.x >> 6] = m;
  __syncthreads();
  __shared__ float sb;
  if (threadIdx.x == 0) {
    float mm = fmaxf(fmaxf(red[0], red[1]), fmaxf(red[2], red[3]));
    sb = mm;
    if (blockIdx.x == 0) scal[SL_AX_X] = mm;
  }
  __syncthreads();
  float s = mk_scale(sb);
  int tid = blockIdx.x * blockDim.x + threadIdx.x;
  int stride = gridDim.x * blockDim.x;
  const float4* x4 = (const float4*)x;
  uint2* o2 = (uint2*)o;
  for (int j = tid; j < (NEL >> 2); j += stride) {
    float4 v = x4[j];
    u16 a = f2b_exact(quant_val(v.x, s));
    u16 b = f2b_exact(quant_val(v.y, s));
    u16 c = f2b_exact(quant_val(v.z, s));
    u16 d = f2b_exact(quant_val(v.w, s));
    uint2 w; w.x = (u32)a | ((u32)b << 16); w.y = (u32)c | ((u32)d << 16);
    o2[j] = w;
  }
}

// generic f32 -> bf16-int quant with scale slot (used for ctx)
__global__ void k_quant_f32(const float* __restrict__ x, u16* __restrict__ o, const float* __restrict__ slot) {
  float s = mk_scale(*slot);
  int tid = blockIdx.x * blockDim.x + threadIdx.x;
  int stride = gridDim.x * blockDim.x;
  const float4* x4 = (const float4*)x;
  uint2* o2 = (uint2*)o;
  for (int j = tid; j < (NEL >> 2); j += stride) {
    float4 v = x4[j];
    u16 a = f2b_exact(quant_val(v.x, s));
    u16 b = f2b_exact(quant_val(v.y, s));
    u16 c = f2b_exact(quant_val(v.z, s));
    u16 d = f2b_exact(quant_val(v.w, s));
    uint2 w; w.x = (u32)a | ((u32)b << 16); w.y = (u32)c | ((u32)d << 16);
    o2[j] = w;
  }
}

// single-block reduction of per-block partials -> one scalar
__global__ void k_reduce(const float* __restrict__ arr, int n, float* __restrict__ slot, int isMin) {
  int tid = threadIdx.x;
  float v = isMin ? __uint_as_float(0x7f800000u) : 0.0f;
  for (int i = tid; i < n; i += 256) {
    float x = arr[i];
    v = isMin ? fminf(v, x) : fmaxf(v, x);
  }
#pragma unroll
  for (int off = 32; off > 0; off >>= 1) {
    float o = __shfl_down(v, off);
    v = isMin ? fminf(v, o) : fmaxf(v, o);
  }
  __shared__ float red[4];
  if ((tid & 63) == 0) red[tid >> 6] = v;
  __syncthreads();
  if (tid == 0) {
    v = isMin ? fminf(fminf(red[0], red[1]), fminf(red[2], red[3]))
              : fmaxf(fmaxf(red[0], red[1]), fmaxf(red[2], red[3]));
    slot[0] = v;
  }
}

// QKV gemms — 256M x 128N tile, 8 waves (512 thr): per-wave 64x64 sub-tile (acc[4][4],
// VGPR ~76 unchanged), LDS 48KB -> 3 blocks/CU = 24 waves/CU, HALF the blocks of R13.
// Same verified gload16 + both-sides XOR swizzle. Barrier-drain count halved; 2x TLP to hide it.
__global__ __launch_bounds__(512, 6) void k_gemm3(const u16* __restrict__ A, const u16* __restrict__ Bw0,
    const float* __restrict__ axslot, const float* __restrict__ sw, GP gp,
    float* __restrict__ outbase, int zoff, int zmul) {
  __shared__ u16 As[256][64];
  __shared__ u16 Bs[128][64];
  int z = blockIdx.z + zoff;
  const u16* Bw = Bw0 + (size_t)z * 1048576;
  const float* sb = sw + z * 1024;
  const float* bias = gp.bias[z];
  float* outf = outbase + (zmul ? (size_t)z * NEL : 0);
  int tid = threadIdx.x;
  int bm = blockIdx.x << 8, bn = blockIdx.y << 7;
  int wv = tid >> 6, lane = tid & 63, quad = lane >> 4, l16 = lane & 15;
  int wr = (wv >> 1) << 6, wc = (wv & 1) << 6;   // 4M x 2N wave grid
  int rsh = lane >> 3;
  int scol = (((lane & 7) ^ rsh) << 3);          // XOR-swizzled source chunk (involution)
  const u16* Ag = A + (size_t)(bm + wv * 32 + rsh) * 1024 + scol;
  const u16* Bg = Bw + (size_t)(bn + wv * 16 + rsh) * 1024 + scol;
  f32x4 zero = {0.f, 0.f, 0.f, 0.f};
  f32x4 acc[4][4];
#pragma unroll
  for (int i = 0; i < 4; i++)
#pragma unroll
    for (int j = 0; j < 4; j++) acc[i][j] = zero;
  for (int k0 = 0; k0 < 1024; k0 += 64) {
    __syncthreads();
#pragma unroll
    for (int i = 0; i < 4; i++)
      gload16(Ag + k0 + (size_t)i * 8 * 1024, &As[wv * 32 + i * 8][0]);
#pragma unroll
    for (int i = 0; i < 2; i++)
      gload16(Bg + k0 + (size_t)i * 8 * 1024, &Bs[wv * 16 + i * 8][0]);
    __syncthreads();
#pragma unroll
    for (int ks = 0; ks < 2; ks++) {
      int swo = ((ks * 4 + quad) ^ (l16 & 7)) << 3;   // swizzled read: chunk ^ (row&7)
      bfx8 af[4], bfr[4];
#pragma unroll
      for (int i = 0; i < 4; i++) {
        af[i] = *(const bfx8*)&As[wr + i * 16 + l16][swo];
        bfr[i] = *(const bfx8*)&Bs[wc + i * 16 + l16][swo];
      }
#pragma unroll
      for (int i = 0; i < 4; i++)
#pragma unroll
        for (int j = 0; j < 4; j++)
          acc[i][j] = __builtin_amdgcn_mfma_f32_16x16x32_bf16(af[i], bfr[j], acc[i][j], 0, 0, 0);
    }
  }
  float sa = mk_scale(*axslot);
  float am0 = 0.f, am1 = 0.f;
#pragma unroll
  for (int j = 0; j < 4; j++) {
    int col = bn + wc + j * 16 + l16;
    float sc = __fmul_rn(sa, sb[col]);
    float bi = bias[col];
#pragma unroll
    for (int i = 0; i < 4; i++) {
      int row0 = bm + wr + i * 16 + quad * 4;
#pragma unroll
      for (int r = 0; r < 4; r++) {
        float v = __fadd_rn(__fmul_rn(acc[i][j][r], sc), bi);
        float av = fabsf(v);
        if (i < 2) am0 = fmaxf(am0, av); else am1 = fmaxf(am1, av);
        int row = row0 + r;
        int b = row >> 9, s2 = row & 511, h = col >> 6, d = col & 63;
        outf[((((size_t)b * NHD) + h) * SS + s2) * DD + d] = v;
      }
    }
  }
  float* axout = gp.ax[z];
  if (z < 2) {
#pragma unroll
    for (int off = 32; off > 0; off >>= 1) {
      am0 = fmaxf(am0, __shfl_down(am0, off));
      am1 = fmaxf(am1, __shfl_down(am1, off));
    }
    if (lane == 0) {
      int t0 = ((bm + wr) >> 5) & 15;   // bm+wr multiple of 64 -> covers tiles t0, t0+1
      atomicMax((u32*)&axout[t0], __float_as_uint(am0));
      atomicMax((u32*)&axout[t0 + 1], __float_as_uint(am1));
    }
  } else {
    float am = fmaxf(am0, am1);
#pragma unroll
    for (int off = 32; off > 0; off >>= 1) am = fmaxf(am, __shfl_down(am, off));
    if (lane == 0) atomicMax((u32*)axout, __float_as_uint(am));
  }
}

// fused quant of q (tiles), k (tiles), vT
__global__ void k_quant3(const float* __restrict__ srcbase, int zoff, int zmul,
                         u16* __restrict__ qq, u16* __restrict__ kq, u16* __restrict__ vqt,
                         const float* __restrict__ scal) {
  __shared__ u16 lds[64][136];
  int zi = zoff + (zmul ? (int)(blockIdx.x >> 10) : 0);
  int b = zmul ? (int)(blockIdx.x & 1023) : (int)blockIdx.x;
  const float* src = srcbase + (zmul ? (size_t)zi * NEL : 0);
  if (zi < 2) {
    const float* slots = scal + (zi == 0 ? SL_AX_QT : SL_AX_KT);
    u16* o = zi == 0 ? qq : kq;
    int tid = b * 256 + threadIdx.x;
    const float4* x4 = (const float4*)src;
    uint2* o2 = (uint2*)o;
    for (int j = tid; j < (NEL >> 2); j += 1024 * 256) {
      int e = j << 2;
      float s = mk_scale(slots[(e >> 11) & 15]);
      float4 v = x4[j];
      u16 a = f2b_exact(quant_val(v.x, s));
      u16 bb = f2b_exact(quant_val(v.y, s));
      u16 c = f2b_exact(quant_val(v.z, s));
      u16 d = f2b_exact(quant_val(v.w, s));
      uint2 w; w.x = (u32)a | ((u32)bb << 16); w.y = (u32)c | ((u32)d << 16);
      o2[j] = w;
    }
    return;
  }
  float s = mk_scale(scal[SL_AX_V]);
  int bh = b >> 2;
  int sc0 = (b & 3) << 7;
  const float4* src4 = (const float4*)(src + ((size_t)bh * SS + sc0) * DD);
  for (int j = threadIdx.x; j < 2048; j += 256) {
    float4 v = src4[j];
    int e = j << 2;
    int srow = e >> 6, d = e & 63;
    lds[d][srow] = f2b_exact(quant_val(v.x, s));
    lds[d + 1][srow] = f2b_exact(quant_val(v.y, s));
    lds[d + 2][srow] = f2b_exact(quant_val(v.z, s));
    lds[d + 3][srow] = f2b_exact(quant_val(v.w, s));
  }
  __syncthreads();
  int d = threadIdx.x >> 2, s0 = (threadIdx.x & 3) << 5;
  u16* dst = vqt + ((size_t)bh * DD + d) * SS + sc0 + s0;
#pragma unroll
  for (int i = 0; i < 32; i += 8)
    *(uint4*)(dst + i) = *(const uint4*)&lds[d][s0 + i];
}

// final projection gemm — same 256x128 / 8-wave structure
__global__ __launch_bounds__(512, 6) void k_gemm_out(const u16* __restrict__ A, const u16* __restrict__ Bw,
    const float* __restrict__ axslot, const float* __restrict__ sb, const float* __restrict__ bias,
    float* __restrict__ outc) {
  __shared__ u16 As[256][64];
  __shared__ u16 Bs[128][64];
  int tid = threadIdx.x;
  int bm = blockIdx.x << 8, bn = blockIdx.y << 7;
  int wv = tid >> 6, lane = tid & 63, quad = lane >> 4, l16 = lane & 15;
  int wr = (wv >> 1) << 6, wc = (wv & 1) << 6;
  int rsh = lane >> 3;
  int scol = (((lane & 7) ^ rsh) << 3);
  const u16* Ag = A + (size_t)(bm + wv * 32 + rsh) * 1024 + scol;
  const u16* Bg = Bw + (size_t)(bn + wv * 16 + rsh) * 1024 + scol;
  f32x4 zero = {0.f, 0.f, 0.f, 0.f};
  f32x4 acc[4][4];
#pragma unroll
  for (int i = 0; i < 4; i++)
#pragma unroll
    for (int j = 0; j < 4; j++) acc[i][j] = zero;
  for (int k0 = 0; k0 < 1024; k0 += 64) {
    __syncthreads();
#pragma unroll
    for (int i = 0; i < 4; i++)
      gload16(Ag + k0 + (size_t)i * 8 * 1024, &As[wv * 32 + i * 8][0]);
#pragma unroll
    for (int i = 0; i < 2; i++)
      gload16(Bg + k0 + (size_t)i * 8 * 1024, &Bs[wv * 16 + i * 8][0]);
    __syncthreads();
#pragma unroll
    for (int ks = 0; ks < 2; ks++) {
      int swo = ((ks * 4 + quad) ^ (l16 & 7)) << 3;
      bfx8 af[4], bfr[4];
#pragma unroll
      for (int i = 0; i < 4; i++) {
        af[i] = *(const bfx8*)&As[wr + i * 16 + l16][swo];
        bfr[i] = *(const bfx8*)&Bs[wc + i * 16 + l16][swo];
      }
#pragma unroll
      for (int i = 0; i < 4; i++)
#pragma unroll
        for (int j = 0; j < 4; j++)
          acc[i][j] = __builtin_amdgcn_mfma_f32_16x16x32_bf16(af[i], bfr[j], acc[i][j], 0, 0, 0);
    }
  }
  float sa = mk_scale(*axslot);
#pragma unroll
  for (int j = 0; j < 4; j++) {
    int col = bn + wc + j * 16 + l16;
    float sc = __fmul_rn(sa, sb[col]);
    float bi = bias[col];
#pragma unroll
    for (int i = 0; i < 4; i++) {
      int row0 = bm + wr + i * 16 + quad * 4;
#pragma unroll
      for (int r = 0; r < 4; r++) {
        float v = __fadd_rn(__fmul_rn(acc[i][j][r], sc), bi);
        outc[(size_t)(row0 + r) * HD + col] = v;
      }
    }
  }
}

// pass 1: rowmax + PLA row sums (scores in registers); K staged via gload16 + swizzle (R17).
__global__ __launch_bounds__(256, 2) void k_attn1(const u16* __restrict__ qq, const u16* __restrict__ kq,
    const float* __restrict__ scal, float* __restrict__ minarr,
    float* __restrict__ rowmax, float* __restrict__ rowsum, PLA pla) {
  __shared__ u16 Ks[256 * 64];       // linear; content chunk-swizzled: LDS[r][c] = K[r][c^(r&7)]
  __shared__ float2 tbl2[12];
  __shared__ float redmin[4];
  int tid = threadIdx.x;
  if (tid < 12) tbl2[tid] = make_float2(pla.m[tid], pla.c[tid]);
  int bh = blockIdx.x >> 3;
  int q0 = (blockIdx.x & 7) << 6;
  int wv = tid >> 6, lane = tid & 63, quad = lane >> 4, l16 = lane & 15;
  int rowb = q0 + wv * 16;
  const u16* qbase = qq + ((size_t)bh * SS + rowb) * DD;
  const u16* kg = kq + (size_t)bh * SS * DD;
  bfx8 a0 = *(const bfx8*)(qbase + l16 * DD + quad * 8);
  bfx8 a1 = *(const bfx8*)(qbase + l16 * DD + 32 + quad * 8);
  float sqv = mk_scale(scal[SL_AX_QT + (rowb >> 5)]);
  const u16* Kg0 = kg + (size_t)(wv * 64 + (lane >> 3)) * 64 + (((lane & 7) ^ (lane >> 3)) << 3);
  int swb0 = (quad ^ (l16 & 7)) << 3;
  int swb1 = ((quad + 4) ^ (l16 & 7)) << 3;
  f32x4 sreg[32];
  float rm[4] = {-INFINITY, -INFINITY, -INFINITY, -INFINITY};
#pragma unroll
  for (int half = 0; half < 2; half++) {
    __syncthreads();
#pragma unroll
    for (int i = 0; i < 8; i++)
      gload16(Kg0 + (size_t)(half * 256 + i * 8) * 64, &Ks[(wv * 64 + i * 8) * 64]);
    __syncthreads();
#pragma unroll
    for (int t = 0; t < 8; t++) {
      float sk = mk_scale(scal[SL_AX_KT + half * 8 + t]);
      float sc = __fmul_rn(__fmul_rn(0.125f, sqv), sk);
#pragma unroll
      for (int h = 0; h < 2; h++) {
        int cbl = t * 2 + h;
        bfx8 b0 = *(const bfx8*)&Ks[(cbl * 16 + l16) * 64 + swb0];
        bfx8 b1 = *(const bfx8*)&Ks[(cbl * 16 + l16) * 64 + swb1];
        f32x4 acc = {0.f, 0.f, 0.f, 0.f};
        acc = __builtin_amdgcn_mfma_f32_16x16x32_bf16(a0, b0, acc, 0, 0, 0);
        acc = __builtin_amdgcn_mfma_f32_16x16x32_bf16(a1, b1, acc, 0, 0, 0);
        int cb = half * 16 + cbl;
#pragma unroll
        for (int r = 0; r < 4; r++) {
          float sv_ = __fmul_rn(acc[r], sc);
          sreg[cb][r] = sv_;
          rm[r] = fmaxf(rm[r], sv_);
        }
      }
    }
  }
#pragma unroll
  for (int m = 1; m < 16; m <<= 1)
#pragma unroll
    for (int r = 0; r < 4; r++) rm[r] = fmaxf(rm[r], __shfl_xor(rm[r], m));
  float sums[4] = {0.f, 0.f, 0.f, 0.f};
#pragma unroll
  for (int cb = 0; cb < 32; cb++)
#pragma unroll
    for (int r = 0; r < 4; r++) {
      float xc = fmaxf(__fsub_rn(sreg[cb][r], rm[r]), -10.0f);
      sums[r] = __fadd_rn(sums[r], pla3(xc, tbl2));
    }
#pragma unroll
  for (int m = 1; m < 16; m <<= 1)
#pragma unroll
    for (int r = 0; r < 4; r++) sums[r] += __shfl_xor(sums[r], m);
  if (l16 == 0) {
#pragma unroll
    for (int r = 0; r < 4; r++) {
      int row = bh * SS + rowb + quad * 4 + r;
      rowmax[row] = rm[r];
      rowsum[row] = sums[r];
    }
  }
  float mn = fminf(fminf(sums[0], sums[1]), fminf(sums[2], sums[3]));
#pragma unroll
  for (int m = 16; m < 64; m <<= 1) mn = fminf(mn, __shfl_xor(mn, m));
  if (lane == 0) redmin[wv] = mn;
  __syncthreads();
  if (tid == 0) {
    mn = fminf(fminf(redmin[0], redmin[1]), fminf(redmin[2], redmin[3]));
    minarr[blockIdx.x] = mn;
  }
}

// pass 2: K and V staged through shared KV union buffer (R13, verified).
__global__ __launch_bounds__(256, 4) void k_attn2(const u16* __restrict__ qq, const u16* __restrict__ kq,
    const u16* __restrict__ vqt, const float* __restrict__ scal, const float* __restrict__ rowmax,
    const float* __restrict__ rowsum, float* __restrict__ ctx, float* __restrict__ maxarr, PLA pla) {
  __shared__ u16 KV[16384];          // union: K-half [256][64] OR V-half [64][256] (32 KB)
  __shared__ u16 P[32][264];
  __shared__ float2 tbl2[12];
  __shared__ float redc[4];
  int tid = threadIdx.x;
  if (tid < 12) tbl2[tid] = make_float2(pla.m[tid], pla.c[tid]);
  int blk = blockIdx.x;
  int bh = blk >> 4;
  int q0 = (blk & 15) << 5;
  int wv = tid >> 6, lane = tid & 63, quad = lane >> 4, l16 = lane & 15;
  int rb = (wv >> 1) * 16;
  int cw = wv & 1;
  float sqv = mk_scale(scal[SL_AX_QT + (q0 >> 5)]);
  float minsum = scal[SL_MINSUM];
  float sv = mk_scale(scal[SL_AX_V]);
  float mxsm = pla.c[11] / (minsum + 1e-9f);
  float scp = mk_scale(mxsm);
  float scv[8];
#pragma unroll
  for (int h2 = 0; h2 < 2; h2++)
#pragma unroll
    for (int z = 0; z < 4; z++)
      scv[h2 * 4 + z] = __fmul_rn(__fmul_rn(0.125f, sqv),
                                  mk_scale(scal[SL_AX_KT + h2 * 8 + cw * 4 + z]));
  const u16* qbase = qq + ((size_t)bh * SS + q0 + rb) * DD;
  const u16* kbase = kq + (size_t)bh * SS * DD;
  const u16* vb = vqt + (size_t)bh * DD * SS;
  bfx8 a0 = *(const bfx8*)(qbase + l16 * DD + quad * 8);
  bfx8 a1 = *(const bfx8*)(qbase + l16 * DD + 32 + quad * 8);
  float nrmx[4], Rr[4];
#pragma unroll
  for (int r = 0; r < 4; r++) {
    int row = bh * SS + q0 + rb + quad * 4 + r;
    nrmx[r] = -rowmax[row];
    Rr[r] = 1.0f / __fmul_rn(rowsum[row] + 1e-9f, scp);
  }
  const u16* Kg0 = kbase + (size_t)(wv * 64 + (lane >> 3)) * 64 + (((lane & 7) ^ (lane >> 3)) << 3);
  int vlc = lane & 31;
  int vdo = lane >> 5;
  f32x4 acc2[2];
  f32x4 zero = {0.f, 0.f, 0.f, 0.f};
  acc2[0] = zero; acc2[1] = zero;
  int swb0 = (quad ^ (l16 & 7)) << 3;
  int swb1 = ((quad + 4) ^ (l16 & 7)) << 3;
#pragma unroll
  for (int h2 = 0; h2 < 2; h2++) {
    __syncthreads();   // prior half's V reads complete before K overwrites
#pragma unroll
    for (int i = 0; i < 8; i++)
      gload16(Kg0 + (size_t)(h2 * 256 + i * 8) * 64, &KV[(wv * 64 + i * 8) * 64]);
    __syncthreads();   // K resident
#pragma unroll
    for (int i = 0; i < 8; i++) {
      int cb_l = cw * 8 + i;
      float sc = scv[h2 * 4 + (i >> 1)];
      bfx8 b0 = *(const bfx8*)&KV[(cb_l * 16 + l16) * 64 + swb0];
      bfx8 b1 = *(const bfx8*)&KV[(cb_l * 16 + l16) * 64 + swb1];
      f32x4 acc = {0.f, 0.f, 0.f, 0.f};
      acc = __builtin_amdgcn_mfma_f32_16x16x32_bf16(a0, b0, acc, 0, 0, 0);
      acc = __builtin_amdgcn_mfma_f32_16x16x32_bf16(a1, b1, acc, 0, 0, 0);
#pragma unroll
      for (int r = 0; r < 4; r++) {
        float sh = __fmaf_rn(acc[r], sc, nrmx[r]);
        float xc = fmaxf(sh, -10.0f);
        float e = pla3(xc, tbl2);
        float np = fminf(rintf(__fmul_rn(e, Rr[r])), 127.0f);
        P[rb + quad * 4 + r][cb_l * 16 + l16] = f2b_exact(np);
      }
    }
    __syncthreads();   // P visible; K reads done -> safe to overwrite KV with V
#pragma unroll
    for (int i = 0; i < 8; i++) {
      int d = wv * 16 + i * 2 + vdo;
      gload16(vb + (size_t)d * SS + h2 * 256 + (((vlc ^ (d & 7))) << 3),
              &KV[(wv * 16 + i * 2) * 256]);
    }
    __syncthreads();   // V resident
#pragma unroll
    for (int ks = 0; ks < 8; ks++) {
      bfx8 pa = *(const bfx8*)&P[rb + l16][ks * 32 + quad * 8];
#pragma unroll
      for (int j = 0; j < 2; j++) {
        int d = cw * 32 + j * 16 + l16;
        bfx8 vf = *(const bfx8*)&KV[d * 256 + ((((ks * 4 + quad) ^ (l16 & 7))) << 3)];
        acc2[j] = __builtin_amdgcn_mfma_f32_16x16x32_bf16(pa, vf, acc2[j], 0, 0, 0);
      }
    }
  }
  float fsc = __fmul_rn(scp, sv);
  int b = bh >> 4, h = bh & 15;
  float am = 0.f;
#pragma unroll
  for (int j = 0; j < 2; j++) {
    int d = cw * 32 + j * 16 + l16;
#pragma unroll
    for (int r = 0; r < 4; r++) {
      int srow = q0 + rb + quad * 4 + r;
      float vvv = __fmul_rn(acc2[j][r], fsc);
      ctx[((size_t)(b * SS + srow)) * HD + h * DD + d] = vvv;
      am = fmaxf(am, fabsf(vvv));
    }
  }
#pragma unroll
  for (int off = 32; off > 0; off >>= 1) am = fmaxf(am, __shfl_down(am, off));
  if (lane == 0) redc[wv] = am;
  __syncthreads();
  if (tid == 0) {
    am = fmaxf(fmaxf(redc[0], redc[1]), fmaxf(redc[2], redc[3]));
    maxarr[blockIdx.x] = am;
  }
}

// host: rebuild _build_pla exactly
static void build_pla(PLA* p) {
  double xs[1001], ys[1001];
  for (int i = 0; i < 1001; i++) { double t = (double)i * 0.01; xs[i] = t - 10.0; }
  xs[1000] = 0.0;
  for (int i = 0; i < 1001; i++) ys[i] = exp(xs[i]);
  double es = 10.0 / 12.0;
  double edges[13];
  for (int i = 0; i < 13; i++) { double t = (double)i * es; edges[i] = t - 10.0; }
  edges[12] = 0.0;
  for (int k = 0; k < 12; k++) {
    double sx = 0, sy = 0, sxx = 0, sxy = 0; int n = 0;
    for (int j = 0; j < 1001; j++) {
      if (xs[j] >= edges[k] && xs[j] <= edges[k + 1]) {
        n++; sx += xs[j]; sy += ys[j]; sxx += xs[j] * xs[j]; sxy += xs[j] * ys[j];
      }
    }
    double mx = sx / n, my = sy / n;
    double mm = (sxy - sx * my) / (sxx - sx * mx);
    double cc = my - mm * mx;
    p->m[k] = (float)mm; p->c[k] = (float)cc; p->a[k] = (float)edges[k];
  }
}

extern "C" void kernel_launch(void* const* d_in, const int* in_sizes, int n_in,
                              void* d_out, int out_size, void* d_ws, size_t ws_size,
                              hipStream_t stream) {
  const float* hs = (const float*)d_in[0];
  const float* Wq = (const float*)d_in[1]; const float* bq = (const float*)d_in[2];
  const float* Wk = (const float*)d_in[3]; const float* bk = (const float*)d_in[4];
  const float* Wv = (const float*)d_in[5]; const float* bv = (const float*)d_in[6];
  const float* Wo = (const float*)d_in[7]; const float* bo = (const float*)d_in[8];
  float* out = (float*)d_out;
  char* ws = (char*)d_ws;
  float* scal = (float*)ws;                         // 64 scalar slots
  float* sw = (float*)(ws + 4096);                  // 4*1024 per-row weight scales
  float* minarr = (float*)(ws + (32 << 10));        // 2048 f32
  float* maxarr = (float*)(ws + (40 << 10));        // 4096 f32
  float* hsax = (float*)(ws + (56 << 10));          // 512 f32 hs absmax partials
  float* rowmax = (float*)(ws + (64 << 10));        // 131072 f32
  float* rowsum = (float*)(ws + (576 << 10));       // 131072 f32
  u16* wb = (u16*)(ws + (2ll << 20));               // 4 x [1024,1024] bf16-int
  u16* xq = (u16*)(ws + (10ll << 20));              // [8192,1024] (reused as ctxq)
  u16* qq = (u16*)(ws + (26ll << 20));              // [B,H,S,D]
  u16* kq = (u16*)(ws + (42ll << 20));              // [B,H,S,D]
  u16* vqt = (u16*)(ws + (58ll << 20));             // [B,H,D,S]
  float* tmp = (float*)(ws + (74ll << 20));         // [8192,1024] fp32 (x3 if fused; then ctx)
  u16* ctxq = xq;

  PLA pla;
  build_pla(&pla);
  WP wp; wp.W[0] = Wq; wp.W[1] = Wk; wp.W[2] = Wv; wp.W[3] = Wo;
  GP gp; gp.bias[0] = bq; gp.bias[1] = bk; gp.bias[2] = bv;
  gp.ax[0] = scal + SL_AX_QT; gp.ax[1] = scal + SL_AX_KT; gp.ax[2] = scal + SL_AX_V;

  k_prep<<<4609, 256, 0, stream>>>(wp, sw, wb, scal, hs, hsax);
  k_quant_hs<<<1024, 256, 0, stream>>>(hs, xq, hsax, scal);

  bool fused = ws_size >= (170ll << 20);
  if (fused) {
    k_gemm3<<<dim3(32, 8, 3), 512, 0, stream>>>(xq, wb, scal + SL_AX_X, sw, gp, tmp, 0, 1);
    k_quant3<<<3072, 256, 0, stream>>>(tmp, 0, 1, qq, kq, vqt, scal);
  } else {
    for (int z = 0; z < 3; z++) {
      k_gemm3<<<dim3(32, 8, 1), 512, 0, stream>>>(xq, wb, scal + SL_AX_X, sw, gp, tmp, z, 0);
      k_quant3<<<1024, 256, 0, stream>>>(tmp, z, 0, qq, kq, vqt, scal);
    }
  }

  k_attn1<<<2048, 256, 0, stream>>>(qq, kq, scal, minarr, rowmax, rowsum, pla);
  k_reduce<<<1, 256, 0, stream>>>(minarr, 2048, scal + SL_MINSUM, 1);
  k_attn2<<<4096, 256, 0, stream>>>(qq, kq, vqt, scal, rowmax, rowsum, tmp, maxarr, pla);
  k_reduce<<<1, 256, 0, stream>>>(maxarr, 4096, scal + SL_AX_CTX, 0);

  k_quant_f32<<<1024, 256, 0, stream>>>(tmp, ctxq, scal + SL_AX_CTX);
  k_gemm_out<<<dim3(32, 8), 512, 0, stream>>>(ctxq, wb + 3145728, scal + SL_AX_CTX,
                                              sw + 3072, bo, out);
}

// Round 19
// 391.672 us; speedup vs baseline: 1.9825x; 1.9825x over previous
//
#include <hip/hip_runtime.h>
#include <math.h>

typedef unsigned short u16;
typedef unsigned int u32;
typedef __bf16 bfx8 __attribute__((ext_vector_type(8)));
typedef float f32x4 __attribute__((ext_vector_type(4)));

#define NB 16
#define SS 512
#define NHD 16
#define DD 64
#define HD 1024
#define NROWS 8192
#define NEL 8388608  // 8192*1024

// scalar slots in ws (floats)
#define SL_AX_X 0
#define SL_AX_V 1
#define SL_MINSUM 2
#define SL_AX_CTX 3
#define SL_AX_QT 4   // 16 slots
#define SL_AX_KT 20  // 16 slots

struct PLA { float m[12]; float c[12]; float a[12]; };
struct WP { const float* W[4]; };
struct GP { const float* bias[3]; float* ax[3]; };

__device__ __forceinline__ u16 f2b_exact(float f) { return (u16)(__float_as_uint(f) >> 16); }
__device__ __forceinline__ float mk_scale(float mx) { float s = mx / 127.0f; return (s == 0.0f) ? 1.0f : s; }
__device__ __forceinline__ float quant_val(float x, float s) {
  return fminf(fmaxf(rintf(x / s), -127.0f), 127.0f);
}
// pla3: single-load PLA (guess by fma+trunc, no correction load) — accepted ~1e-4 ctx noise.
__device__ __forceinline__ float pla3(float xc, const float2* tbl2) {
  int idx = (int)__fmaf_rn(xc, 1.2f, 12.0f);
  idx = idx < 0 ? 0 : (idx > 11 ? 11 : idx);
  float2 mc = tbl2[idx];
  return __fmaf_rn(mc.x, xc, mc.y);
}

// async global->LDS, 16B per lane (m97 staging primitive)
__device__ __forceinline__ void gload16(const u16* g, u16* l) {
  __builtin_amdgcn_global_load_lds(
      (const __attribute__((address_space(1))) unsigned int*)g,
      (__attribute__((address_space(3))) unsigned int*)l, 16, 0, 0);
}

// fused: blocks [0,4096) = per-row weight quant (4 matrices); 4096 = scal init;
// (4096,4608] = hs absmax partials (plain stores).
__global__ void k_prep(WP wp, float* __restrict__ sw, u16* __restrict__ wout,
                       float* __restrict__ scal, const float* __restrict__ hs,
                       float* __restrict__ hsax) {
  __shared__ float red[4];
  __shared__ float sbc;
  int tid = threadIdx.x;
  if (blockIdx.x == 4096) {
    if (tid < 64) scal[tid] = (tid == SL_MINSUM) ? __uint_as_float(0x7f800000u) : 0.0f;
    return;
  }
  if (blockIdx.x > 4096) {
    int pb = blockIdx.x - 4097;
    int t = pb * 256 + tid;
    const float4* x4 = (const float4*)hs;
    float m = 0.f;
    for (int j = t; j < (NEL >> 2); j += 512 * 256) {
      float4 v = x4[j];
      m = fmaxf(m, fmaxf(fmaxf(fabsf(v.x), fabsf(v.y)), fmaxf(fabsf(v.z), fabsf(v.w))));
    }
#pragma unroll
    for (int off = 32; off > 0; off >>= 1) m = fmaxf(m, __shfl_down(m, off));
    if ((tid & 63) == 0) red[tid >> 6] = m;
    __syncthreads();
    if (tid == 0) hsax[pb] = fmaxf(fmaxf(red[0], red[1]), fmaxf(red[2], red[3]));
    return;
  }
  int mat = blockIdx.x >> 10, r = blockIdx.x & 1023;
  const float* W = wp.W[mat];
  float4 v = ((const float4*)(W + (size_t)r * 1024))[tid];
  float m = fmaxf(fmaxf(fabsf(v.x), fabsf(v.y)), fmaxf(fabsf(v.z), fabsf(v.w)));
#pragma unroll
  for (int off = 32; off > 0; off >>= 1) m = fmaxf(m, __shfl_down(m, off));
  int lane = tid & 63, wv = tid >> 6;
  if (lane == 0) red[wv] = m;
  __syncthreads();
  if (tid == 0) sbc = mk_scale(fmaxf(fmaxf(red[0], red[1]), fmaxf(red[2], red[3])));
  __syncthreads();
  float s = sbc;
  if (tid == 0) sw[mat * 1024 + r] = s;
  u16 o0 = f2b_exact(quant_val(v.x, s));
  u16 o1 = f2b_exact(quant_val(v.y, s));
  u16 o2 = f2b_exact(quant_val(v.z, s));
  u16 o3 = f2b_exact(quant_val(v.w, s));
  u32* orow = (u32*)(wout + (size_t)mat * 1048576 + (size_t)r * 1024);
  orow[tid * 2] = (u32)o0 | ((u32)o1 << 16);
  orow[tid * 2 + 1] = (u32)o2 | ((u32)o3 << 16);
}

// quantize hs with scale from 512 partials; block 0 publishes scal[SL_AX_X]
__global__ void k_quant_hs(const float* __restrict__ x, u16* __restrict__ o,
                           const float* __restrict__ hsax, float* __restrict__ scal) {
  float m = 0.f;
  for (int i = threadIdx.x; i < 512; i += 256) m = fmaxf(m, hsax[i]);
#pragma unroll
  for (int off = 32; off > 0; off >>= 1) m = fmaxf(m, __shfl_down(m, off));
  __shared__ float red[4];
  if ((threadIdx.x & 63) == 0) red[threadIdx.x >> 6] = m;
  __syncthreads();
  __shared__ float sb;
  if (threadIdx.x == 0) {
    float mm = fmaxf(fmaxf(red[0], red[1]), fmaxf(red[2], red[3]));
    sb = mm;
    if (blockIdx.x == 0) scal[SL_AX_X] = mm;
  }
  __syncthreads();
  float s = mk_scale(sb);
  int tid = blockIdx.x * blockDim.x + threadIdx.x;
  int stride = gridDim.x * blockDim.x;
  const float4* x4 = (const float4*)x;
  uint2* o2 = (uint2*)o;
  for (int j = tid; j < (NEL >> 2); j += stride) {
    float4 v = x4[j];
    u16 a = f2b_exact(quant_val(v.x, s));
    u16 b = f2b_exact(quant_val(v.y, s));
    u16 c = f2b_exact(quant_val(v.z, s));
    u16 d = f2b_exact(quant_val(v.w, s));
    uint2 w; w.x = (u32)a | ((u32)b << 16); w.y = (u32)c | ((u32)d << 16);
    o2[j] = w;
  }
}

// generic f32 -> bf16-int quant with scale slot (used for ctx)
__global__ void k_quant_f32(const float* __restrict__ x, u16* __restrict__ o, const float* __restrict__ slot) {
  float s = mk_scale(*slot);
  int tid = blockIdx.x * blockDim.x + threadIdx.x;
  int stride = gridDim.x * blockDim.x;
  const float4* x4 = (const float4*)x;
  uint2* o2 = (uint2*)o;
  for (int j = tid; j < (NEL >> 2); j += stride) {
    float4 v = x4[j];
    u16 a = f2b_exact(quant_val(v.x, s));
    u16 b = f2b_exact(quant_val(v.y, s));
    u16 c = f2b_exact(quant_val(v.z, s));
    u16 d = f2b_exact(quant_val(v.w, s));
    uint2 w; w.x = (u32)a | ((u32)b << 16); w.y = (u32)c | ((u32)d << 16);
    o2[j] = w;
  }
}

// single-block reduction of per-block partials -> one scalar
__global__ void k_reduce(const float* __restrict__ arr, int n, float* __restrict__ slot, int isMin) {
  int tid = threadIdx.x;
  float v = isMin ? __uint_as_float(0x7f800000u) : 0.0f;
  for (int i = tid; i < n; i += 256) {
    float x = arr[i];
    v = isMin ? fminf(v, x) : fmaxf(v, x);
  }
#pragma unroll
  for (int off = 32; off > 0; off >>= 1) {
    float o = __shfl_down(v, off);
    v = isMin ? fminf(v, o) : fmaxf(v, o);
  }
  __shared__ float red[4];
  if ((tid & 63) == 0) red[tid >> 6] = v;
  __syncthreads();
  if (tid == 0) {
    v = isMin ? fminf(fminf(red[0], red[1]), fminf(red[2], red[3]))
              : fmaxf(fmaxf(red[0], red[1]), fmaxf(red[2], red[3]));
    slot[0] = v;
  }
}

// QKV gemms — R13/R17 body verbatim (best measured ~109us; identity block mapping).
__global__ __launch_bounds__(256, 3) void k_gemm3(const u16* __restrict__ A, const u16* __restrict__ Bw0,
    const float* __restrict__ axslot, const float* __restrict__ sw, GP gp,
    float* __restrict__ outbase, int zoff, int zmul) {
  __shared__ u16 As[128][64];
  __shared__ u16 Bs[128][64];
  int z = blockIdx.z + zoff;
  const u16* Bw = Bw0 + (size_t)z * 1048576;
  const float* sb = sw + z * 1024;
  const float* bias = gp.bias[z];
  float* outf = outbase + (zmul ? (size_t)z * NEL : 0);
  int tid = threadIdx.x;
  int bm = blockIdx.x << 7, bn = blockIdx.y << 7;
  int wv = tid >> 6, lane = tid & 63, quad = lane >> 4, l16 = lane & 15;
  int wr = (wv >> 1) << 6, wc = (wv & 1) << 6;
  int srow = wv * 32 + (lane >> 3);
  int scol = (((lane & 7) ^ (lane >> 3)) << 3);   // XOR-swizzled source chunk (involution)
  const u16* Ag = A + (size_t)(bm + srow) * 1024 + scol;
  const u16* Bg = Bw + (size_t)(bn + srow) * 1024 + scol;
  f32x4 zero = {0.f, 0.f, 0.f, 0.f};
  f32x4 acc[4][4];
#pragma unroll
  for (int i = 0; i < 4; i++)
#pragma unroll
    for (int j = 0; j < 4; j++) acc[i][j] = zero;
  for (int k0 = 0; k0 < 1024; k0 += 64) {
    __syncthreads();
#pragma unroll
    for (int i = 0; i < 4; i++) {
      gload16(Ag + k0 + (size_t)i * 8 * 1024, &As[wv * 32 + i * 8][0]);
      gload16(Bg + k0 + (size_t)i * 8 * 1024, &Bs[wv * 32 + i * 8][0]);
    }
    __syncthreads();
#pragma unroll
    for (int ks = 0; ks < 2; ks++) {
      int swo = ((ks * 4 + quad) ^ (l16 & 7)) << 3;   // swizzled read: chunk ^ (row&7)
      bfx8 af[4], bfr[4];
#pragma unroll
      for (int i = 0; i < 4; i++) {
        af[i] = *(const bfx8*)&As[wr + i * 16 + l16][swo];
        bfr[i] = *(const bfx8*)&Bs[wc + i * 16 + l16][swo];
      }
#pragma unroll
      for (int i = 0; i < 4; i++)
#pragma unroll
        for (int j = 0; j < 4; j++)
          acc[i][j] = __builtin_amdgcn_mfma_f32_16x16x32_bf16(af[i], bfr[j], acc[i][j], 0, 0, 0);
    }
  }
  float sa = mk_scale(*axslot);
  float am0 = 0.f, am1 = 0.f;
#pragma unroll
  for (int j = 0; j < 4; j++) {
    int col = bn + wc + j * 16 + l16;
    float sc = __fmul_rn(sa, sb[col]);
    float bi = bias[col];
#pragma unroll
    for (int i = 0; i < 4; i++) {
      int row0 = bm + wr + i * 16 + quad * 4;
#pragma unroll
      for (int r = 0; r < 4; r++) {
        float v = __fadd_rn(__fmul_rn(acc[i][j][r], sc), bi);
        float av = fabsf(v);
        if (i < 2) am0 = fmaxf(am0, av); else am1 = fmaxf(am1, av);
        int row = row0 + r;
        int b = row >> 9, s2 = row & 511, h = col >> 6, d = col & 63;
        outf[((((size_t)b * NHD) + h) * SS + s2) * DD + d] = v;
      }
    }
  }
  float* axout = gp.ax[z];
  if (z < 2) {
#pragma unroll
    for (int off = 32; off > 0; off >>= 1) {
      am0 = fmaxf(am0, __shfl_down(am0, off));
      am1 = fmaxf(am1, __shfl_down(am1, off));
    }
    if (lane == 0) {
      int t0 = ((bm + wr) >> 5) & 15;
      atomicMax((u32*)&axout[t0], __float_as_uint(am0));
      atomicMax((u32*)&axout[t0 + 1], __float_as_uint(am1));
    }
  } else {
    float am = fmaxf(am0, am1);
#pragma unroll
    for (int off = 32; off > 0; off >>= 1) am = fmaxf(am, __shfl_down(am, off));
    if (lane == 0) atomicMax((u32*)axout, __float_as_uint(am));
  }
}

// fused quant of q (tiles), k (tiles), vT
__global__ void k_quant3(const float* __restrict__ srcbase, int zoff, int zmul,
                         u16* __restrict__ qq, u16* __restrict__ kq, u16* __restrict__ vqt,
                         const float* __restrict__ scal) {
  __shared__ u16 lds[64][136];
  int zi = zoff + (zmul ? (int)(blockIdx.x >> 10) : 0);
  int b = zmul ? (int)(blockIdx.x & 1023) : (int)blockIdx.x;
  const float* src = srcbase + (zmul ? (size_t)zi * NEL : 0);
  if (zi < 2) {
    const float* slots = scal + (zi == 0 ? SL_AX_QT : SL_AX_KT);
    u16* o = zi == 0 ? qq : kq;
    int tid = b * 256 + threadIdx.x;
    const float4* x4 = (const float4*)src;
    uint2* o2 = (uint2*)o;
    for (int j = tid; j < (NEL >> 2); j += 1024 * 256) {
      int e = j << 2;
      float s = mk_scale(slots[(e >> 11) & 15]);
      float4 v = x4[j];
      u16 a = f2b_exact(quant_val(v.x, s));
      u16 bb = f2b_exact(quant_val(v.y, s));
      u16 c = f2b_exact(quant_val(v.z, s));
      u16 d = f2b_exact(quant_val(v.w, s));
      uint2 w; w.x = (u32)a | ((u32)bb << 16); w.y = (u32)c | ((u32)d << 16);
      o2[j] = w;
    }
    return;
  }
  float s = mk_scale(scal[SL_AX_V]);
  int bh = b >> 2;
  int sc0 = (b & 3) << 7;
  const float4* src4 = (const float4*)(src + ((size_t)bh * SS + sc0) * DD);
  for (int j = threadIdx.x; j < 2048; j += 256) {
    float4 v = src4[j];
    int e = j << 2;
    int srow = e >> 6, d = e & 63;
    lds[d][srow] = f2b_exact(quant_val(v.x, s));
    lds[d + 1][srow] = f2b_exact(quant_val(v.y, s));
    lds[d + 2][srow] = f2b_exact(quant_val(v.z, s));
    lds[d + 3][srow] = f2b_exact(quant_val(v.w, s));
  }
  __syncthreads();
  int d = threadIdx.x >> 2, s0 = (threadIdx.x & 3) << 5;
  u16* dst = vqt + ((size_t)bh * DD + d) * SS + sc0 + s0;
#pragma unroll
  for (int i = 0; i < 32; i += 8)
    *(uint4*)(dst + i) = *(const uint4*)&lds[d][s0 + i];
}

// final projection gemm — R13/R17 body verbatim
__global__ __launch_bounds__(256, 3) void k_gemm_out(const u16* __restrict__ A, const u16* __restrict__ Bw,
    const float* __restrict__ axslot, const float* __restrict__ sb, const float* __restrict__ bias,
    float* __restrict__ outc) {
  __shared__ u16 As[128][64];
  __shared__ u16 Bs[128][64];
  int tid = threadIdx.x;
  int bm = blockIdx.x << 7, bn = blockIdx.y << 7;
  int wv = tid >> 6, lane = tid & 63, quad = lane >> 4, l16 = lane & 15;
  int wr = (wv >> 1) << 6, wc = (wv & 1) << 6;
  int srow = wv * 32 + (lane >> 3);
  int scol = (((lane & 7) ^ (lane >> 3)) << 3);
  const u16* Ag = A + (size_t)(bm + srow) * 1024 + scol;
  const u16* Bg = Bw + (size_t)(bn + srow) * 1024 + scol;
  f32x4 zero = {0.f, 0.f, 0.f, 0.f};
  f32x4 acc[4][4];
#pragma unroll
  for (int i = 0; i < 4; i++)
#pragma unroll
    for (int j = 0; j < 4; j++) acc[i][j] = zero;
  for (int k0 = 0; k0 < 1024; k0 += 64) {
    __syncthreads();
#pragma unroll
    for (int i = 0; i < 4; i++) {
      gload16(Ag + k0 + (size_t)i * 8 * 1024, &As[wv * 32 + i * 8][0]);
      gload16(Bg + k0 + (size_t)i * 8 * 1024, &Bs[wv * 32 + i * 8][0]);
    }
    __syncthreads();
#pragma unroll
    for (int ks = 0; ks < 2; ks++) {
      int swo = ((ks * 4 + quad) ^ (l16 & 7)) << 3;
      bfx8 af[4], bfr[4];
#pragma unroll
      for (int i = 0; i < 4; i++) {
        af[i] = *(const bfx8*)&As[wr + i * 16 + l16][swo];
        bfr[i] = *(const bfx8*)&Bs[wc + i * 16 + l16][swo];
      }
#pragma unroll
      for (int i = 0; i < 4; i++)
#pragma unroll
        for (int j = 0; j < 4; j++)
          acc[i][j] = __builtin_amdgcn_mfma_f32_16x16x32_bf16(af[i], bfr[j], acc[i][j], 0, 0, 0);
    }
  }
  float sa = mk_scale(*axslot);
#pragma unroll
  for (int j = 0; j < 4; j++) {
    int col = bn + wc + j * 16 + l16;
    float sc = __fmul_rn(sa, sb[col]);
    float bi = bias[col];
#pragma unroll
    for (int i = 0; i < 4; i++) {
      int row0 = bm + wr + i * 16 + quad * 4;
#pragma unroll
      for (int r = 0; r < 4; r++) {
        float v = __fadd_rn(__fmul_rn(acc[i][j][r], sc), bi);
        outc[(size_t)(row0 + r) * HD + col] = v;
      }
    }
  }
}

// pass 1: rowmax + PLA row sums (scores in registers); K staged via gload16 + swizzle (R17).
__global__ __launch_bounds__(256, 2) void k_attn1(const u16* __restrict__ qq, const u16* __restrict__ kq,
    const float* __restrict__ scal, float* __restrict__ minarr,
    float* __restrict__ rowmax, float* __restrict__ rowsum, PLA pla) {
  __shared__ u16 Ks[256 * 64];       // linear; content chunk-swizzled: LDS[r][c] = K[r][c^(r&7)]
  __shared__ float2 tbl2[12];
  __shared__ float redmin[4];
  int tid = threadIdx.x;
  if (tid < 12) tbl2[tid] = make_float2(pla.m[tid], pla.c[tid]);
  int bh = blockIdx.x >> 3;
  int q0 = (blockIdx.x & 7) << 6;
  int wv = tid >> 6, lane = tid & 63, quad = lane >> 4, l16 = lane & 15;
  int rowb = q0 + wv * 16;
  const u16* qbase = qq + ((size_t)bh * SS + rowb) * DD;
  const u16* kg = kq + (size_t)bh * SS * DD;
  bfx8 a0 = *(const bfx8*)(qbase + l16 * DD + quad * 8);
  bfx8 a1 = *(const bfx8*)(qbase + l16 * DD + 32 + quad * 8);
  float sqv = mk_scale(scal[SL_AX_QT + (rowb >> 5)]);
  const u16* Kg0 = kg + (size_t)(wv * 64 + (lane >> 3)) * 64 + (((lane & 7) ^ (lane >> 3)) << 3);
  int swb0 = (quad ^ (l16 & 7)) << 3;
  int swb1 = ((quad + 4) ^ (l16 & 7)) << 3;
  f32x4 sreg[32];
  float rm[4] = {-INFINITY, -INFINITY, -INFINITY, -INFINITY};
#pragma unroll
  for (int half = 0; half < 2; half++) {
    __syncthreads();
#pragma unroll
    for (int i = 0; i < 8; i++)
      gload16(Kg0 + (size_t)(half * 256 + i * 8) * 64, &Ks[(wv * 64 + i * 8) * 64]);
    __syncthreads();
#pragma unroll
    for (int t = 0; t < 8; t++) {
      float sk = mk_scale(scal[SL_AX_KT + half * 8 + t]);
      float sc = __fmul_rn(__fmul_rn(0.125f, sqv), sk);
#pragma unroll
      for (int h = 0; h < 2; h++) {
        int cbl = t * 2 + h;
        bfx8 b0 = *(const bfx8*)&Ks[(cbl * 16 + l16) * 64 + swb0];
        bfx8 b1 = *(const bfx8*)&Ks[(cbl * 16 + l16) * 64 + swb1];
        f32x4 acc = {0.f, 0.f, 0.f, 0.f};
        acc = __builtin_amdgcn_mfma_f32_16x16x32_bf16(a0, b0, acc, 0, 0, 0);
        acc = __builtin_amdgcn_mfma_f32_16x16x32_bf16(a1, b1, acc, 0, 0, 0);
        int cb = half * 16 + cbl;
#pragma unroll
        for (int r = 0; r < 4; r++) {
          float sv_ = __fmul_rn(acc[r], sc);
          sreg[cb][r] = sv_;
          rm[r] = fmaxf(rm[r], sv_);
        }
      }
    }
  }
#pragma unroll
  for (int m = 1; m < 16; m <<= 1)
#pragma unroll
    for (int r = 0; r < 4; r++) rm[r] = fmaxf(rm[r], __shfl_xor(rm[r], m));
  float sums[4] = {0.f, 0.f, 0.f, 0.f};
#pragma unroll
  for (int cb = 0; cb < 32; cb++)
#pragma unroll
    for (int r = 0; r < 4; r++) {
      float xc = fmaxf(__fsub_rn(sreg[cb][r], rm[r]), -10.0f);
      sums[r] = __fadd_rn(sums[r], pla3(xc, tbl2));
    }
#pragma unroll
  for (int m = 1; m < 16; m <<= 1)
#pragma unroll
    for (int r = 0; r < 4; r++) sums[r] += __shfl_xor(sums[r], m);
  if (l16 == 0) {
#pragma unroll
    for (int r = 0; r < 4; r++) {
      int row = bh * SS + rowb + quad * 4 + r;
      rowmax[row] = rm[r];
      rowsum[row] = sums[r];
    }
  }
  float mn = fminf(fminf(sums[0], sums[1]), fminf(sums[2], sums[3]));
#pragma unroll
  for (int m = 16; m < 64; m <<= 1) mn = fminf(mn, __shfl_xor(mn, m));
  if (lane == 0) redmin[wv] = mn;
  __syncthreads();
  if (tid == 0) {
    mn = fminf(fminf(redmin[0], redmin[1]), fminf(redmin[2], redmin[3]));
    minarr[blockIdx.x] = mn;
  }
}

// pass 2: K and V staged through shared KV union buffer (R13, verified).
__global__ __launch_bounds__(256, 4) void k_attn2(const u16* __restrict__ qq, const u16* __restrict__ kq,
    const u16* __restrict__ vqt, const float* __restrict__ scal, const float* __restrict__ rowmax,
    const float* __restrict__ rowsum, float* __restrict__ ctx, float* __restrict__ maxarr, PLA pla) {
  __shared__ u16 KV[16384];          // union: K-half [256][64] OR V-half [64][256] (32 KB)
  __shared__ u16 P[32][264];
  __shared__ float2 tbl2[12];
  __shared__ float redc[4];
  int tid = threadIdx.x;
  if (tid < 12) tbl2[tid] = make_float2(pla.m[tid], pla.c[tid]);
  int blk = blockIdx.x;
  int bh = blk >> 4;
  int q0 = (blk & 15) << 5;
  int wv = tid >> 6, lane = tid & 63, quad = lane >> 4, l16 = lane & 15;
  int rb = (wv >> 1) * 16;
  int cw = wv & 1;
  float sqv = mk_scale(scal[SL_AX_QT + (q0 >> 5)]);
  float minsum = scal[SL_MINSUM];
  float sv = mk_scale(scal[SL_AX_V]);
  float mxsm = pla.c[11] / (minsum + 1e-9f);
  float scp = mk_scale(mxsm);
  float scv[8];
#pragma unroll
  for (int h2 = 0; h2 < 2; h2++)
#pragma unroll
    for (int z = 0; z < 4; z++)
      scv[h2 * 4 + z] = __fmul_rn(__fmul_rn(0.125f, sqv),
                                  mk_scale(scal[SL_AX_KT + h2 * 8 + cw * 4 + z]));
  const u16* qbase = qq + ((size_t)bh * SS + q0 + rb) * DD;
  const u16* kbase = kq + (size_t)bh * SS * DD;
  const u16* vb = vqt + (size_t)bh * DD * SS;
  bfx8 a0 = *(const bfx8*)(qbase + l16 * DD + quad * 8);
  bfx8 a1 = *(const bfx8*)(qbase + l16 * DD + 32 + quad * 8);
  float nrmx[4], Rr[4];
#pragma unroll
  for (int r = 0; r < 4; r++) {
    int row = bh * SS + q0 + rb + quad * 4 + r;
    nrmx[r] = -rowmax[row];
    Rr[r] = 1.0f / __fmul_rn(rowsum[row] + 1e-9f, scp);
  }
  const u16* Kg0 = kbase + (size_t)(wv * 64 + (lane >> 3)) * 64 + (((lane & 7) ^ (lane >> 3)) << 3);
  int vlc = lane & 31;
  int vdo = lane >> 5;
  f32x4 acc2[2];
  f32x4 zero = {0.f, 0.f, 0.f, 0.f};
  acc2[0] = zero; acc2[1] = zero;
  int swb0 = (quad ^ (l16 & 7)) << 3;
  int swb1 = ((quad + 4) ^ (l16 & 7)) << 3;
#pragma unroll
  for (int h2 = 0; h2 < 2; h2++) {
    __syncthreads();   // prior half's V reads complete before K overwrites
#pragma unroll
    for (int i = 0; i < 8; i++)
      gload16(Kg0 + (size_t)(h2 * 256 + i * 8) * 64, &KV[(wv * 64 + i * 8) * 64]);
    __syncthreads();   // K resident
#pragma unroll
    for (int i = 0; i < 8; i++) {
      int cb_l = cw * 8 + i;
      float sc = scv[h2 * 4 + (i >> 1)];
      bfx8 b0 = *(const bfx8*)&KV[(cb_l * 16 + l16) * 64 + swb0];
      bfx8 b1 = *(const bfx8*)&KV[(cb_l * 16 + l16) * 64 + swb1];
      f32x4 acc = {0.f, 0.f, 0.f, 0.f};
      acc = __builtin_amdgcn_mfma_f32_16x16x32_bf16(a0, b0, acc, 0, 0, 0);
      acc = __builtin_amdgcn_mfma_f32_16x16x32_bf16(a1, b1, acc, 0, 0, 0);
#pragma unroll
      for (int r = 0; r < 4; r++) {
        float sh = __fmaf_rn(acc[r], sc, nrmx[r]);
        float xc = fmaxf(sh, -10.0f);
        float e = pla3(xc, tbl2);
        float np = fminf(rintf(__fmul_rn(e, Rr[r])), 127.0f);
        P[rb + quad * 4 + r][cb_l * 16 + l16] = f2b_exact(np);
      }
    }
    __syncthreads();   // P visible; K reads done -> safe to overwrite KV with V
#pragma unroll
    for (int i = 0; i < 8; i++) {
      int d = wv * 16 + i * 2 + vdo;
      gload16(vb + (size_t)d * SS + h2 * 256 + (((vlc ^ (d & 7))) << 3),
              &KV[(wv * 16 + i * 2) * 256]);
    }
    __syncthreads();   // V resident
#pragma unroll
    for (int ks = 0; ks < 8; ks++) {
      bfx8 pa = *(const bfx8*)&P[rb + l16][ks * 32 + quad * 8];
#pragma unroll
      for (int j = 0; j < 2; j++) {
        int d = cw * 32 + j * 16 + l16;
        bfx8 vf = *(const bfx8*)&KV[d * 256 + ((((ks * 4 + quad) ^ (l16 & 7))) << 3)];
        acc2[j] = __builtin_amdgcn_mfma_f32_16x16x32_bf16(pa, vf, acc2[j], 0, 0, 0);
      }
    }
  }
  float fsc = __fmul_rn(scp, sv);
  int b = bh >> 4, h = bh & 15;
  float am = 0.f;
#pragma unroll
  for (int j = 0; j < 2; j++) {
    int d = cw * 32 + j * 16 + l16;
#pragma unroll
    for (int r = 0; r < 4; r++) {
      int srow = q0 + rb + quad * 4 + r;
      float vvv = __fmul_rn(acc2[j][r], fsc);
      ctx[((size_t)(b * SS + srow)) * HD + h * DD + d] = vvv;
      am = fmaxf(am, fabsf(vvv));
    }
  }
#pragma unroll
  for (int off = 32; off > 0; off >>= 1) am = fmaxf(am, __shfl_down(am, off));
  if (lane == 0) redc[wv] = am;
  __syncthreads();
  if (tid == 0) {
    am = fmaxf(fmaxf(redc[0], redc[1]), fmaxf(redc[2], redc[3]));
    maxarr[blockIdx.x] = am;
  }
}

// host: rebuild _build_pla exactly
static void build_pla(PLA* p) {
  double xs[1001], ys[1001];
  for (int i = 0; i < 1001; i++) { double t = (double)i * 0.01; xs[i] = t - 10.0; }
  xs[1000] = 0.0;
  for (int i = 0; i < 1001; i++) ys[i] = exp(xs[i]);
  double es = 10.0 / 12.0;
  double edges[13];
  for (int i = 0; i < 13; i++) { double t = (double)i * es; edges[i] = t - 10.0; }
  edges[12] = 0.0;
  for (int k = 0; k < 12; k++) {
    double sx = 0, sy = 0, sxx = 0, sxy = 0; int n = 0;
    for (int j = 0; j < 1001; j++) {
      if (xs[j] >= edges[k] && xs[j] <= edges[k + 1]) {
        n++; sx += xs[j]; sy += ys[j]; sxx += xs[j] * xs[j]; sxy += xs[j] * ys[j];
      }
    }
    double mx = sx / n, my = sy / n;
    double mm = (sxy - sx * my) / (sxx - sx * mx);
    double cc = my - mm * mx;
    p->m[k] = (float)mm; p->c[k] = (float)cc; p->a[k] = (float)edges[k];
  }
}

extern "C" void kernel_launch(void* const* d_in, const int* in_sizes, int n_in,
                              void* d_out, int out_size, void* d_ws, size_t ws_size,
                              hipStream_t stream) {
  const float* hs = (const float*)d_in[0];
  const float* Wq = (const float*)d_in[1]; const float* bq = (const float*)d_in[2];
  const float* Wk = (const float*)d_in[3]; const float* bk = (const float*)d_in[4];
  const float* Wv = (const float*)d_in[5]; const float* bv = (const float*)d_in[6];
  const float* Wo = (const float*)d_in[7]; const float* bo = (const float*)d_in[8];
  float* out = (float*)d_out;
  char* ws = (char*)d_ws;
  float* scal = (float*)ws;                         // 64 scalar slots
  float* sw = (float*)(ws + 4096);                  // 4*1024 per-row weight scales
  float* minarr = (float*)(ws + (32 << 10));        // 2048 f32
  float* maxarr = (float*)(ws + (40 << 10));        // 4096 f32
  float* hsax = (float*)(ws + (56 << 10));          // 512 f32 hs absmax partials
  float* rowmax = (float*)(ws + (64 << 10));        // 131072 f32
  float* rowsum = (float*)(ws + (576 << 10));       // 131072 f32
  u16* wb = (u16*)(ws + (2ll << 20));               // 4 x [1024,1024] bf16-int
  u16* xq = (u16*)(ws + (10ll << 20));              // [8192,1024] (reused as ctxq)
  u16* qq = (u16*)(ws + (26ll << 20));              // [B,H,S,D]
  u16* kq = (u16*)(ws + (42ll << 20));              // [B,H,S,D]
  u16* vqt = (u16*)(ws + (58ll << 20));             // [B,H,D,S]
  float* tmp = (float*)(ws + (74ll << 20));         // [8192,1024] fp32 (x3 if fused; then ctx)
  u16* ctxq = xq;

  PLA pla;
  build_pla(&pla);
  WP wp; wp.W[0] = Wq; wp.W[1] = Wk; wp.W[2] = Wv; wp.W[3] = Wo;
  GP gp; gp.bias[0] = bq; gp.bias[1] = bk; gp.bias[2] = bv;
  gp.ax[0] = scal + SL_AX_QT; gp.ax[1] = scal + SL_AX_KT; gp.ax[2] = scal + SL_AX_V;

  k_prep<<<4609, 256, 0, stream>>>(wp, sw, wb, scal, hs, hsax);
  k_quant_hs<<<1024, 256, 0, stream>>>(hs, xq, hsax, scal);

  bool fused = ws_size >= (170ll << 20);
  if (fused) {
    k_gemm3<<<dim3(64, 8, 3), 256, 0, stream>>>(xq, wb, scal + SL_AX_X, sw, gp, tmp, 0, 1);
    k_quant3<<<3072, 256, 0, stream>>>(tmp, 0, 1, qq, kq, vqt, scal);
  } else {
    for (int z = 0; z < 3; z++) {
      k_gemm3<<<dim3(64, 8, 1), 256, 0, stream>>>(xq, wb, scal + SL_AX_X, sw, gp, tmp, z, 0);
      k_quant3<<<1024, 256, 0, stream>>>(tmp, z, 0, qq, kq, vqt, scal);
    }
  }

  k_attn1<<<2048, 256, 0, stream>>>(qq, kq, scal, minarr, rowmax, rowsum, pla);
  k_reduce<<<1, 256, 0, stream>>>(minarr, 2048, scal + SL_MINSUM, 1);
  k_attn2<<<4096, 256, 0, stream>>>(qq, kq, vqt, scal, rowmax, rowsum, tmp, maxarr, pla);
  k_reduce<<<1, 256, 0, stream>>>(maxarr, 4096, scal + SL_AX_CTX, 0);

  k_quant_f32<<<1024, 256, 0, stream>>>(tmp, ctxq, scal + SL_AX_CTX);
  k_gemm_out<<<dim3(64, 8), 256, 0, stream>>>(ctxq, wb + 3145728, scal + SL_AX_CTX,
                                              sw + 3072, bo, out);
}

// Round 20
// 390.941 us; speedup vs baseline: 1.9862x; 1.0019x over previous
//
#include <hip/hip_runtime.h>
#include <math.h>

typedef unsigned short u16;
typedef unsigned int u32;
typedef __bf16 bfx8 __attribute__((ext_vector_type(8)));
typedef float f32x4 __attribute__((ext_vector_type(4)));

#define NB 16
#define SS 512
#define NHD 16
#define DD 64
#define HD 1024
#define NROWS 8192
#define NEL 8388608  // 8192*1024

// scalar slots in ws (floats)
#define SL_AX_X 0
#define SL_AX_V 1
#define SL_MINSUM 2
#define SL_AX_CTX 3
#define SL_AX_QT 4   // 16 slots
#define SL_AX_KT 20  // 16 slots

struct PLA { float m[12]; float c[12]; float a[12]; };
struct WP { const float* W[4]; };
struct GP { const float* bias[3]; float* ax[3]; };

__device__ __forceinline__ u16 f2b_exact(float f) { return (u16)(__float_as_uint(f) >> 16); }
__device__ __forceinline__ float mk_scale(float mx) { float s = mx / 127.0f; return (s == 0.0f) ? 1.0f : s; }
__device__ __forceinline__ float quant_val(float x, float s) {
  return fminf(fmaxf(rintf(x / s), -127.0f), 127.0f);
}
// pla3: single-load PLA (guess by fma+trunc, no correction load) — accepted ~1e-4 ctx noise.
__device__ __forceinline__ float pla3(float xc, const float2* tbl2) {
  int idx = (int)__fmaf_rn(xc, 1.2f, 12.0f);
  idx = idx < 0 ? 0 : (idx > 11 ? 11 : idx);
  float2 mc = tbl2[idx];
  return __fmaf_rn(mc.x, xc, mc.y);
}

// async global->LDS, 16B per lane (m97 staging primitive)
__device__ __forceinline__ void gload16(const u16* g, u16* l) {
  __builtin_amdgcn_global_load_lds(
      (const __attribute__((address_space(1))) unsigned int*)g,
      (__attribute__((address_space(3))) unsigned int*)l, 16, 0, 0);
}

// fused: blocks [0,4096) = per-row weight quant (4 matrices); 4096 = scal init;
// (4096,4608] = hs absmax partials (plain stores).
__global__ void k_prep(WP wp, float* __restrict__ sw, u16* __restrict__ wout,
                       float* __restrict__ scal, const float* __restrict__ hs,
                       float* __restrict__ hsax) {
  __shared__ float red[4];
  __shared__ float sbc;
  int tid = threadIdx.x;
  if (blockIdx.x == 4096) {
    if (tid < 64) scal[tid] = (tid == SL_MINSUM) ? __uint_as_float(0x7f800000u) : 0.0f;
    return;
  }
  if (blockIdx.x > 4096) {
    int pb = blockIdx.x - 4097;
    int t = pb * 256 + tid;
    const float4* x4 = (const float4*)hs;
    float m = 0.f;
    for (int j = t; j < (NEL >> 2); j += 512 * 256) {
      float4 v = x4[j];
      m = fmaxf(m, fmaxf(fmaxf(fabsf(v.x), fabsf(v.y)), fmaxf(fabsf(v.z), fabsf(v.w))));
    }
#pragma unroll
    for (int off = 32; off > 0; off >>= 1) m = fmaxf(m, __shfl_down(m, off));
    if ((tid & 63) == 0) red[tid >> 6] = m;
    __syncthreads();
    if (tid == 0) hsax[pb] = fmaxf(fmaxf(red[0], red[1]), fmaxf(red[2], red[3]));
    return;
  }
  int mat = blockIdx.x >> 10, r = blockIdx.x & 1023;
  const float* W = wp.W[mat];
  float4 v = ((const float4*)(W + (size_t)r * 1024))[tid];
  float m = fmaxf(fmaxf(fabsf(v.x), fabsf(v.y)), fmaxf(fabsf(v.z), fabsf(v.w)));
#pragma unroll
  for (int off = 32; off > 0; off >>= 1) m = fmaxf(m, __shfl_down(m, off));
  int lane = tid & 63, wv = tid >> 6;
  if (lane == 0) red[wv] = m;
  __syncthreads();
  if (tid == 0) sbc = mk_scale(fmaxf(fmaxf(red[0], red[1]), fmaxf(red[2], red[3])));
  __syncthreads();
  float s = sbc;
  if (tid == 0) sw[mat * 1024 + r] = s;
  u16 o0 = f2b_exact(quant_val(v.x, s));
  u16 o1 = f2b_exact(quant_val(v.y, s));
  u16 o2 = f2b_exact(quant_val(v.z, s));
  u16 o3 = f2b_exact(quant_val(v.w, s));
  u32* orow = (u32*)(wout + (size_t)mat * 1048576 + (size_t)r * 1024);
  orow[tid * 2] = (u32)o0 | ((u32)o1 << 16);
  orow[tid * 2 + 1] = (u32)o2 | ((u32)o3 << 16);
}

// quantize hs with scale from 512 partials; block 0 publishes scal[SL_AX_X]
__global__ void k_quant_hs(const float* __restrict__ x, u16* __restrict__ o,
                           const float* __restrict__ hsax, float* __restrict__ scal) {
  float m = 0.f;
  for (int i = threadIdx.x; i < 512; i += 256) m = fmaxf(m, hsax[i]);
#pragma unroll
  for (int off = 32; off > 0; off >>= 1) m = fmaxf(m, __shfl_down(m, off));
  __shared__ float red[4];
  if ((threadIdx.x & 63) == 0) red[threadIdx.x >> 6] = m;
  __syncthreads();
  __shared__ float sb;
  if (threadIdx.x == 0) {
    float mm = fmaxf(fmaxf(red[0], red[1]), fmaxf(red[2], red[3]));
    sb = mm;
    if (blockIdx.x == 0) scal[SL_AX_X] = mm;
  }
  __syncthreads();
  float s = mk_scale(sb);
  int tid = blockIdx.x * blockDim.x + threadIdx.x;
  int stride = gridDim.x * blockDim.x;
  const float4* x4 = (const float4*)x;
  uint2* o2 = (uint2*)o;
  for (int j = tid; j < (NEL >> 2); j += stride) {
    float4 v = x4[j];
    u16 a = f2b_exact(quant_val(v.x, s));
    u16 b = f2b_exact(quant_val(v.y, s));
    u16 c = f2b_exact(quant_val(v.z, s));
    u16 d = f2b_exact(quant_val(v.w, s));
    uint2 w; w.x = (u32)a | ((u32)b << 16); w.y = (u32)c | ((u32)d << 16);
    o2[j] = w;
  }
}

// generic f32 -> bf16-int quant with scale slot (used for ctx)
__global__ void k_quant_f32(const float* __restrict__ x, u16* __restrict__ o, const float* __restrict__ slot) {
  float s = mk_scale(*slot);
  int tid = blockIdx.x * blockDim.x + threadIdx.x;
  int stride = gridDim.x * blockDim.x;
  const float4* x4 = (const float4*)x;
  uint2* o2 = (uint2*)o;
  for (int j = tid; j < (NEL >> 2); j += stride) {
    float4 v = x4[j];
    u16 a = f2b_exact(quant_val(v.x, s));
    u16 b = f2b_exact(quant_val(v.y, s));
    u16 c = f2b_exact(quant_val(v.z, s));
    u16 d = f2b_exact(quant_val(v.w, s));
    uint2 w; w.x = (u32)a | ((u32)b << 16); w.y = (u32)c | ((u32)d << 16);
    o2[j] = w;
  }
}

// single-block reduction of per-block partials -> one scalar
__global__ void k_reduce(const float* __restrict__ arr, int n, float* __restrict__ slot, int isMin) {
  int tid = threadIdx.x;
  float v = isMin ? __uint_as_float(0x7f800000u) : 0.0f;
  for (int i = tid; i < n; i += 256) {
    float x = arr[i];
    v = isMin ? fminf(v, x) : fmaxf(v, x);
  }
#pragma unroll
  for (int off = 32; off > 0; off >>= 1) {
    float o = __shfl_down(v, off);
    v = isMin ? fminf(v, o) : fmaxf(v, o);
  }
  __shared__ float red[4];
  if ((tid & 63) == 0) red[tid >> 6] = v;
  __syncthreads();
  if (tid == 0) {
    v = isMin ? fminf(fminf(red[0], red[1]), fminf(red[2], red[3]))
              : fmaxf(fmaxf(red[0], red[1]), fmaxf(red[2], red[3]));
    slot[0] = v;
  }
}

// QKV gemms — measured-best body (~108us; identity block mapping, gload16 + XOR swizzle,
// conflicts==0, (256,3): 3 blocks/CU nominal, no spill).
__global__ __launch_bounds__(256, 3) void k_gemm3(const u16* __restrict__ A, const u16* __restrict__ Bw0,
    const float* __restrict__ axslot, const float* __restrict__ sw, GP gp,
    float* __restrict__ outbase, int zoff, int zmul) {
  __shared__ u16 As[128][64];
  __shared__ u16 Bs[128][64];
  int z = blockIdx.z + zoff;
  const u16* Bw = Bw0 + (size_t)z * 1048576;
  const float* sb = sw + z * 1024;
  const float* bias = gp.bias[z];
  float* outf = outbase + (zmul ? (size_t)z * NEL : 0);
  int tid = threadIdx.x;
  int bm = blockIdx.x << 7, bn = blockIdx.y << 7;
  int wv = tid >> 6, lane = tid & 63, quad = lane >> 4, l16 = lane & 15;
  int wr = (wv >> 1) << 6, wc = (wv & 1) << 6;
  int srow = wv * 32 + (lane >> 3);
  int scol = (((lane & 7) ^ (lane >> 3)) << 3);   // XOR-swizzled source chunk (involution)
  const u16* Ag = A + (size_t)(bm + srow) * 1024 + scol;
  const u16* Bg = Bw + (size_t)(bn + srow) * 1024 + scol;
  f32x4 zero = {0.f, 0.f, 0.f, 0.f};
  f32x4 acc[4][4];
#pragma unroll
  for (int i = 0; i < 4; i++)
#pragma unroll
    for (int j = 0; j < 4; j++) acc[i][j] = zero;
  for (int k0 = 0; k0 < 1024; k0 += 64) {
    __syncthreads();
#pragma unroll
    for (int i = 0; i < 4; i++) {
      gload16(Ag + k0 + (size_t)i * 8 * 1024, &As[wv * 32 + i * 8][0]);
      gload16(Bg + k0 + (size_t)i * 8 * 1024, &Bs[wv * 32 + i * 8][0]);
    }
    __syncthreads();
#pragma unroll
    for (int ks = 0; ks < 2; ks++) {
      int swo = ((ks * 4 + quad) ^ (l16 & 7)) << 3;   // swizzled read: chunk ^ (row&7)
      bfx8 af[4], bfr[4];
#pragma unroll
      for (int i = 0; i < 4; i++) {
        af[i] = *(const bfx8*)&As[wr + i * 16 + l16][swo];
        bfr[i] = *(const bfx8*)&Bs[wc + i * 16 + l16][swo];
      }
#pragma unroll
      for (int i = 0; i < 4; i++)
#pragma unroll
        for (int j = 0; j < 4; j++)
          acc[i][j] = __builtin_amdgcn_mfma_f32_16x16x32_bf16(af[i], bfr[j], acc[i][j], 0, 0, 0);
    }
  }
  float sa = mk_scale(*axslot);
  float am0 = 0.f, am1 = 0.f;
#pragma unroll
  for (int j = 0; j < 4; j++) {
    int col = bn + wc + j * 16 + l16;
    float sc = __fmul_rn(sa, sb[col]);
    float bi = bias[col];
#pragma unroll
    for (int i = 0; i < 4; i++) {
      int row0 = bm + wr + i * 16 + quad * 4;
#pragma unroll
      for (int r = 0; r < 4; r++) {
        float v = __fadd_rn(__fmul_rn(acc[i][j][r], sc), bi);
        float av = fabsf(v);
        if (i < 2) am0 = fmaxf(am0, av); else am1 = fmaxf(am1, av);
        int row = row0 + r;
        int b = row >> 9, s2 = row & 511, h = col >> 6, d = col & 63;
        outf[((((size_t)b * NHD) + h) * SS + s2) * DD + d] = v;
      }
    }
  }
  float* axout = gp.ax[z];
  if (z < 2) {
#pragma unroll
    for (int off = 32; off > 0; off >>= 1) {
      am0 = fmaxf(am0, __shfl_down(am0, off));
      am1 = fmaxf(am1, __shfl_down(am1, off));
    }
    if (lane == 0) {
      int t0 = ((bm + wr) >> 5) & 15;
      atomicMax((u32*)&axout[t0], __float_as_uint(am0));
      atomicMax((u32*)&axout[t0 + 1], __float_as_uint(am1));
    }
  } else {
    float am = fmaxf(am0, am1);
#pragma unroll
    for (int off = 32; off > 0; off >>= 1) am = fmaxf(am, __shfl_down(am, off));
    if (lane == 0) atomicMax((u32*)axout, __float_as_uint(am));
  }
}

// fused quant of q (tiles), k (tiles), vT
__global__ void k_quant3(const float* __restrict__ srcbase, int zoff, int zmul,
                         u16* __restrict__ qq, u16* __restrict__ kq, u16* __restrict__ vqt,
                         const float* __restrict__ scal) {
  __shared__ u16 lds[64][136];
  int zi = zoff + (zmul ? (int)(blockIdx.x >> 10) : 0);
  int b = zmul ? (int)(blockIdx.x & 1023) : (int)blockIdx.x;
  const float* src = srcbase + (zmul ? (size_t)zi * NEL : 0);
  if (zi < 2) {
    const float* slots = scal + (zi == 0 ? SL_AX_QT : SL_AX_KT);
    u16* o = zi == 0 ? qq : kq;
    int tid = b * 256 + threadIdx.x;
    const float4* x4 = (const float4*)src;
    uint2* o2 = (uint2*)o;
    for (int j = tid; j < (NEL >> 2); j += 1024 * 256) {
      int e = j << 2;
      float s = mk_scale(slots[(e >> 11) & 15]);
      float4 v = x4[j];
      u16 a = f2b_exact(quant_val(v.x, s));
      u16 bb = f2b_exact(quant_val(v.y, s));
      u16 c = f2b_exact(quant_val(v.z, s));
      u16 d = f2b_exact(quant_val(v.w, s));
      uint2 w; w.x = (u32)a | ((u32)bb << 16); w.y = (u32)c | ((u32)d << 16);
      o2[j] = w;
    }
    return;
  }
  float s = mk_scale(scal[SL_AX_V]);
  int bh = b >> 2;
  int sc0 = (b & 3) << 7;
  const float4* src4 = (const float4*)(src + ((size_t)bh * SS + sc0) * DD);
  for (int j = threadIdx.x; j < 2048; j += 256) {
    float4 v = src4[j];
    int e = j << 2;
    int srow = e >> 6, d = e & 63;
    lds[d][srow] = f2b_exact(quant_val(v.x, s));
    lds[d + 1][srow] = f2b_exact(quant_val(v.y, s));
    lds[d + 2][srow] = f2b_exact(quant_val(v.z, s));
    lds[d + 3][srow] = f2b_exact(quant_val(v.w, s));
  }
  __syncthreads();
  int d = threadIdx.x >> 2, s0 = (threadIdx.x & 3) << 5;
  u16* dst = vqt + ((size_t)bh * DD + d) * SS + sc0 + s0;
#pragma unroll
  for (int i = 0; i < 32; i += 8)
    *(uint4*)(dst + i) = *(const uint4*)&lds[d][s0 + i];
}

// final projection gemm — measured-best body
__global__ __launch_bounds__(256, 3) void k_gemm_out(const u16* __restrict__ A, const u16* __restrict__ Bw,
    const float* __restrict__ axslot, const float* __restrict__ sb, const float* __restrict__ bias,
    float* __restrict__ outc) {
  __shared__ u16 As[128][64];
  __shared__ u16 Bs[128][64];
  int tid = threadIdx.x;
  int bm = blockIdx.x << 7, bn = blockIdx.y << 7;
  int wv = tid >> 6, lane = tid & 63, quad = lane >> 4, l16 = lane & 15;
  int wr = (wv >> 1) << 6, wc = (wv & 1) << 6;
  int srow = wv * 32 + (lane >> 3);
  int scol = (((lane & 7) ^ (lane >> 3)) << 3);
  const u16* Ag = A + (size_t)(bm + srow) * 1024 + scol;
  const u16* Bg = Bw + (size_t)(bn + srow) * 1024 + scol;
  f32x4 zero = {0.f, 0.f, 0.f, 0.f};
  f32x4 acc[4][4];
#pragma unroll
  for (int i = 0; i < 4; i++)
#pragma unroll
    for (int j = 0; j < 4; j++) acc[i][j] = zero;
  for (int k0 = 0; k0 < 1024; k0 += 64) {
    __syncthreads();
#pragma unroll
    for (int i = 0; i < 4; i++) {
      gload16(Ag + k0 + (size_t)i * 8 * 1024, &As[wv * 32 + i * 8][0]);
      gload16(Bg + k0 + (size_t)i * 8 * 1024, &Bs[wv * 32 + i * 8][0]);
    }
    __syncthreads();
#pragma unroll
    for (int ks = 0; ks < 2; ks++) {
      int swo = ((ks * 4 + quad) ^ (l16 & 7)) << 3;
      bfx8 af[4], bfr[4];
#pragma unroll
      for (int i = 0; i < 4; i++) {
        af[i] = *(const bfx8*)&As[wr + i * 16 + l16][swo];
        bfr[i] = *(const bfx8*)&Bs[wc + i * 16 + l16][swo];
      }
#pragma unroll
      for (int i = 0; i < 4; i++)
#pragma unroll
        for (int j = 0; j < 4; j++)
          acc[i][j] = __builtin_amdgcn_mfma_f32_16x16x32_bf16(af[i], bfr[j], acc[i][j], 0, 0, 0);
    }
  }
  float sa = mk_scale(*axslot);
#pragma unroll
  for (int j = 0; j < 4; j++) {
    int col = bn + wc + j * 16 + l16;
    float sc = __fmul_rn(sa, sb[col]);
    float bi = bias[col];
#pragma unroll
    for (int i = 0; i < 4; i++) {
      int row0 = bm + wr + i * 16 + quad * 4;
#pragma unroll
      for (int r = 0; r < 4; r++) {
        float v = __fadd_rn(__fmul_rn(acc[i][j][r], sc), bi);
        outc[(size_t)(row0 + r) * HD + col] = v;
      }
    }
  }
}

// pass 1: rowmax + PLA row sums (scores in registers); K staged via gload16 + swizzle.
__global__ __launch_bounds__(256, 2) void k_attn1(const u16* __restrict__ qq, const u16* __restrict__ kq,
    const float* __restrict__ scal, float* __restrict__ minarr,
    float* __restrict__ rowmax, float* __restrict__ rowsum, PLA pla) {
  __shared__ u16 Ks[256 * 64];       // linear; content chunk-swizzled: LDS[r][c] = K[r][c^(r&7)]
  __shared__ float2 tbl2[12];
  __shared__ float redmin[4];
  int tid = threadIdx.x;
  if (tid < 12) tbl2[tid] = make_float2(pla.m[tid], pla.c[tid]);
  int bh = blockIdx.x >> 3;
  int q0 = (blockIdx.x & 7) << 6;
  int wv = tid >> 6, lane = tid & 63, quad = lane >> 4, l16 = lane & 15;
  int rowb = q0 + wv * 16;
  const u16* qbase = qq + ((size_t)bh * SS + rowb) * DD;
  const u16* kg = kq + (size_t)bh * SS * DD;
  bfx8 a0 = *(const bfx8*)(qbase + l16 * DD + quad * 8);
  bfx8 a1 = *(const bfx8*)(qbase + l16 * DD + 32 + quad * 8);
  float sqv = mk_scale(scal[SL_AX_QT + (rowb >> 5)]);
  const u16* Kg0 = kg + (size_t)(wv * 64 + (lane >> 3)) * 64 + (((lane & 7) ^ (lane >> 3)) << 3);
  int swb0 = (quad ^ (l16 & 7)) << 3;
  int swb1 = ((quad + 4) ^ (l16 & 7)) << 3;
  f32x4 sreg[32];
  float rm[4] = {-INFINITY, -INFINITY, -INFINITY, -INFINITY};
#pragma unroll
  for (int half = 0; half < 2; half++) {
    __syncthreads();
#pragma unroll
    for (int i = 0; i < 8; i++)
      gload16(Kg0 + (size_t)(half * 256 + i * 8) * 64, &Ks[(wv * 64 + i * 8) * 64]);
    __syncthreads();
#pragma unroll
    for (int t = 0; t < 8; t++) {
      float sk = mk_scale(scal[SL_AX_KT + half * 8 + t]);
      float sc = __fmul_rn(__fmul_rn(0.125f, sqv), sk);
#pragma unroll
      for (int h = 0; h < 2; h++) {
        int cbl = t * 2 + h;
        bfx8 b0 = *(const bfx8*)&Ks[(cbl * 16 + l16) * 64 + swb0];
        bfx8 b1 = *(const bfx8*)&Ks[(cbl * 16 + l16) * 64 + swb1];
        f32x4 acc = {0.f, 0.f, 0.f, 0.f};
        acc = __builtin_amdgcn_mfma_f32_16x16x32_bf16(a0, b0, acc, 0, 0, 0);
        acc = __builtin_amdgcn_mfma_f32_16x16x32_bf16(a1, b1, acc, 0, 0, 0);
        int cb = half * 16 + cbl;
#pragma unroll
        for (int r = 0; r < 4; r++) {
          float sv_ = __fmul_rn(acc[r], sc);
          sreg[cb][r] = sv_;
          rm[r] = fmaxf(rm[r], sv_);
        }
      }
    }
  }
#pragma unroll
  for (int m = 1; m < 16; m <<= 1)
#pragma unroll
    for (int r = 0; r < 4; r++) rm[r] = fmaxf(rm[r], __shfl_xor(rm[r], m));
  float sums[4] = {0.f, 0.f, 0.f, 0.f};
#pragma unroll
  for (int cb = 0; cb < 32; cb++)
#pragma unroll
    for (int r = 0; r < 4; r++) {
      float xc = fmaxf(__fsub_rn(sreg[cb][r], rm[r]), -10.0f);
      sums[r] = __fadd_rn(sums[r], pla3(xc, tbl2));
    }
#pragma unroll
  for (int m = 1; m < 16; m <<= 1)
#pragma unroll
    for (int r = 0; r < 4; r++) sums[r] += __shfl_xor(sums[r], m);
  if (l16 == 0) {
#pragma unroll
    for (int r = 0; r < 4; r++) {
      int row = bh * SS + rowb + quad * 4 + r;
      rowmax[row] = rm[r];
      rowsum[row] = sums[r];
    }
  }
  float mn = fminf(fminf(sums[0], sums[1]), fminf(sums[2], sums[3]));
#pragma unroll
  for (int m = 16; m < 64; m <<= 1) mn = fminf(mn, __shfl_xor(mn, m));
  if (lane == 0) redmin[wv] = mn;
  __syncthreads();
  if (tid == 0) {
    mn = fminf(fminf(redmin[0], redmin[1]), fminf(redmin[2], redmin[3]));
    minarr[blockIdx.x] = mn;
  }
}

// pass 2: K and V staged through shared KV union buffer.
__global__ __launch_bounds__(256, 4) void k_attn2(const u16* __restrict__ qq, const u16* __restrict__ kq,
    const u16* __restrict__ vqt, const float* __restrict__ scal, const float* __restrict__ rowmax,
    const float* __restrict__ rowsum, float* __restrict__ ctx, float* __restrict__ maxarr, PLA pla) {
  __shared__ u16 KV[16384];          // union: K-half [256][64] OR V-half [64][256] (32 KB)
  __shared__ u16 P[32][264];
  __shared__ float2 tbl2[12];
  __shared__ float redc[4];
  int tid = threadIdx.x;
  if (tid < 12) tbl2[tid] = make_float2(pla.m[tid], pla.c[tid]);
  int blk = blockIdx.x;
  int bh = blk >> 4;
  int q0 = (blk & 15) << 5;
  int wv = tid >> 6, lane = tid & 63, quad = lane >> 4, l16 = lane & 15;
  int rb = (wv >> 1) * 16;
  int cw = wv & 1;
  float sqv = mk_scale(scal[SL_AX_QT + (q0 >> 5)]);
  float minsum = scal[SL_MINSUM];
  float sv = mk_scale(scal[SL_AX_V]);
  float mxsm = pla.c[11] / (minsum + 1e-9f);
  float scp = mk_scale(mxsm);
  float scv[8];
#pragma unroll
  for (int h2 = 0; h2 < 2; h2++)
#pragma unroll
    for (int z = 0; z < 4; z++)
      scv[h2 * 4 + z] = __fmul_rn(__fmul_rn(0.125f, sqv),
                                  mk_scale(scal[SL_AX_KT + h2 * 8 + cw * 4 + z]));
  const u16* qbase = qq + ((size_t)bh * SS + q0 + rb) * DD;
  const u16* kbase = kq + (size_t)bh * SS * DD;
  const u16* vb = vqt + (size_t)bh * DD * SS;
  bfx8 a0 = *(const bfx8*)(qbase + l16 * DD + quad * 8);
  bfx8 a1 = *(const bfx8*)(qbase + l16 * DD + 32 + quad * 8);
  float nrmx[4], Rr[4];
#pragma unroll
  for (int r = 0; r < 4; r++) {
    int row = bh * SS + q0 + rb + quad * 4 + r;
    nrmx[r] = -rowmax[row];
    Rr[r] = 1.0f / __fmul_rn(rowsum[row] + 1e-9f, scp);
  }
  const u16* Kg0 = kbase + (size_t)(wv * 64 + (lane >> 3)) * 64 + (((lane & 7) ^ (lane >> 3)) << 3);
  int vlc = lane & 31;
  int vdo = lane >> 5;
  f32x4 acc2[2];
  f32x4 zero = {0.f, 0.f, 0.f, 0.f};
  acc2[0] = zero; acc2[1] = zero;
  int swb0 = (quad ^ (l16 & 7)) << 3;
  int swb1 = ((quad + 4) ^ (l16 & 7)) << 3;
#pragma unroll
  for (int h2 = 0; h2 < 2; h2++) {
    __syncthreads();   // prior half's V reads complete before K overwrites
#pragma unroll
    for (int i = 0; i < 8; i++)
      gload16(Kg0 + (size_t)(h2 * 256 + i * 8) * 64, &KV[(wv * 64 + i * 8) * 64]);
    __syncthreads();   // K resident
#pragma unroll
    for (int i = 0; i < 8; i++) {
      int cb_l = cw * 8 + i;
      float sc = scv[h2 * 4 + (i >> 1)];
      bfx8 b0 = *(const bfx8*)&KV[(cb_l * 16 + l16) * 64 + swb0];
      bfx8 b1 = *(const bfx8*)&KV[(cb_l * 16 + l16) * 64 + swb1];
      f32x4 acc = {0.f, 0.f, 0.f, 0.f};
      acc = __builtin_amdgcn_mfma_f32_16x16x32_bf16(a0, b0, acc, 0, 0, 0);
      acc = __builtin_amdgcn_mfma_f32_16x16x32_bf16(a1, b1, acc, 0, 0, 0);
#pragma unroll
      for (int r = 0; r < 4; r++) {
        float sh = __fmaf_rn(acc[r], sc, nrmx[r]);
        float xc = fmaxf(sh, -10.0f);
        float e = pla3(xc, tbl2);
        float np = fminf(rintf(__fmul_rn(e, Rr[r])), 127.0f);
        P[rb + quad * 4 + r][cb_l * 16 + l16] = f2b_exact(np);
      }
    }
    __syncthreads();   // P visible; K reads done -> safe to overwrite KV with V
#pragma unroll
    for (int i = 0; i < 8; i++) {
      int d = wv * 16 + i * 2 + vdo;
      gload16(vb + (size_t)d * SS + h2 * 256 + (((vlc ^ (d & 7))) << 3),
              &KV[(wv * 16 + i * 2) * 256]);
    }
    __syncthreads();   // V resident
#pragma unroll
    for (int ks = 0; ks < 8; ks++) {
      bfx8 pa = *(const bfx8*)&P[rb + l16][ks * 32 + quad * 8];
#pragma unroll
      for (int j = 0; j < 2; j++) {
        int d = cw * 32 + j * 16 + l16;
        bfx8 vf = *(const bfx8*)&KV[d * 256 + ((((ks * 4 + quad) ^ (l16 & 7))) << 3)];
        acc2[j] = __builtin_amdgcn_mfma_f32_16x16x32_bf16(pa, vf, acc2[j], 0, 0, 0);
      }
    }
  }
  float fsc = __fmul_rn(scp, sv);
  int b = bh >> 4, h = bh & 15;
  float am = 0.f;
#pragma unroll
  for (int j = 0; j < 2; j++) {
    int d = cw * 32 + j * 16 + l16;
#pragma unroll
    for (int r = 0; r < 4; r++) {
      int srow = q0 + rb + quad * 4 + r;
      float vvv = __fmul_rn(acc2[j][r], fsc);
      ctx[((size_t)(b * SS + srow)) * HD + h * DD + d] = vvv;
      am = fmaxf(am, fabsf(vvv));
    }
  }
#pragma unroll
  for (int off = 32; off > 0; off >>= 1) am = fmaxf(am, __shfl_down(am, off));
  if (lane == 0) redc[wv] = am;
  __syncthreads();
  if (tid == 0) {
    am = fmaxf(fmaxf(redc[0], redc[1]), fmaxf(redc[2], redc[3]));
    maxarr[blockIdx.x] = am;
  }
}

// host: rebuild _build_pla exactly
static void build_pla(PLA* p) {
  double xs[1001], ys[1001];
  for (int i = 0; i < 1001; i++) { double t = (double)i * 0.01; xs[i] = t - 10.0; }
  xs[1000] = 0.0;
  for (int i = 0; i < 1001; i++) ys[i] = exp(xs[i]);
  double es = 10.0 / 12.0;
  double edges[13];
  for (int i = 0; i < 13; i++) { double t = (double)i * es; edges[i] = t - 10.0; }
  edges[12] = 0.0;
  for (int k = 0; k < 12; k++) {
    double sx = 0, sy = 0, sxx = 0, sxy = 0; int n = 0;
    for (int j = 0; j < 1001; j++) {
      if (xs[j] >= edges[k] && xs[j] <= edges[k + 1]) {
        n++; sx += xs[j]; sy += ys[j]; sxx += xs[j] * xs[j]; sxy += xs[j] * ys[j];
      }
    }
    double mx = sx / n, my = sy / n;
    double mm = (sxy - sx * my) / (sxx - sx * mx);
    double cc = my - mm * mx;
    p->m[k] = (float)mm; p->c[k] = (float)cc; p->a[k] = (float)edges[k];
  }
}

extern "C" void kernel_launch(void* const* d_in, const int* in_sizes, int n_in,
                              void* d_out, int out_size, void* d_ws, size_t ws_size,
                              hipStream_t stream) {
  const float* hs = (const float*)d_in[0];
  const float* Wq = (const float*)d_in[1]; const float* bq = (const float*)d_in[2];
  const float* Wk = (const float*)d_in[3]; const float* bk = (const float*)d_in[4];
  const float* Wv = (const float*)d_in[5]; const float* bv = (const float*)d_in[6];
  const float* Wo = (const float*)d_in[7]; const float* bo = (const float*)d_in[8];
  float* out = (float*)d_out;
  char* ws = (char*)d_ws;
  float* scal = (float*)ws;                         // 64 scalar slots
  float* sw = (float*)(ws + 4096);                  // 4*1024 per-row weight scales
  float* minarr = (float*)(ws + (32 << 10));        // 2048 f32
  float* maxarr = (float*)(ws + (40 << 10));        // 4096 f32
  float* hsax = (float*)(ws + (56 << 10));          // 512 f32 hs absmax partials
  float* rowmax = (float*)(ws + (64 << 10));        // 131072 f32
  float* rowsum = (float*)(ws + (576 << 10));       // 131072 f32
  u16* wb = (u16*)(ws + (2ll << 20));               // 4 x [1024,1024] bf16-int
  u16* xq = (u16*)(ws + (10ll << 20));              // [8192,1024] (reused as ctxq)
  u16* qq = (u16*)(ws + (26ll << 20));              // [B,H,S,D]
  u16* kq = (u16*)(ws + (42ll << 20));              // [B,H,S,D]
  u16* vqt = (u16*)(ws + (58ll << 20));             // [B,H,D,S]
  float* tmp = (float*)(ws + (74ll << 20));         // [8192,1024] fp32 (x3 if fused; then ctx)
  u16* ctxq = xq;

  PLA pla;
  build_pla(&pla);
  WP wp; wp.W[0] = Wq; wp.W[1] = Wk; wp.W[2] = Wv; wp.W[3] = Wo;
  GP gp; gp.bias[0] = bq; gp.bias[1] = bk; gp.bias[2] = bv;
  gp.ax[0] = scal + SL_AX_QT; gp.ax[1] = scal + SL_AX_KT; gp.ax[2] = scal + SL_AX_V;

  k_prep<<<4609, 256, 0, stream>>>(wp, sw, wb, scal, hs, hsax);
  k_quant_hs<<<1024, 256, 0, stream>>>(hs, xq, hsax, scal);

  bool fused = ws_size >= (170ll << 20);
  if (fused) {
    k_gemm3<<<dim3(64, 8, 3), 256, 0, stream>>>(xq, wb, scal + SL_AX_X, sw, gp, tmp, 0, 1);
    k_quant3<<<3072, 256, 0, stream>>>(tmp, 0, 1, qq, kq, vqt, scal);
  } else {
    for (int z = 0; z < 3; z++) {
      k_gemm3<<<dim3(64, 8, 1), 256, 0, stream>>>(xq, wb, scal + SL_AX_X, sw, gp, tmp, z, 0);
      k_quant3<<<1024, 256, 0, stream>>>(tmp, z, 0, qq, kq, vqt, scal);
    }
  }

  k_attn1<<<2048, 256, 0, stream>>>(qq, kq, scal, minarr, rowmax, rowsum, pla);
  k_reduce<<<1, 256, 0, stream>>>(minarr, 2048, scal + SL_MINSUM, 1);
  k_attn2<<<4096, 256, 0, stream>>>(qq, kq, vqt, scal, rowmax, rowsum, tmp, maxarr, pla);
  k_reduce<<<1, 256, 0, stream>>>(maxarr, 4096, scal + SL_AX_CTX, 0);

  k_quant_f32<<<1024, 256, 0, stream>>>(tmp, ctxq, scal + SL_AX_CTX);
  k_gemm_out<<<dim3(64, 8), 256, 0, stream>>>(ctxq, wb + 3145728, scal + SL_AX_CTX,
                                              sw + 3072, bo, out);
}